// Round 1
// baseline (8885.947 us; speedup 1.0000x reference)
//
#include <hip/hip_runtime.h>
#include <hip/hip_bf16.h>
#include <cstddef>

// GPT-2 block, fp32 baseline. B=4 (derived), S=2048, D=1024, H=16, DH=64, FF=4096.
#define SEQ   2048
#define DMODEL 1024
#define NHEAD 16
#define HDIM  64
#define FFDIM 4096

// ---------------------------------------------------------------------------
// LayerNorm: one block per row, 256 threads, float4 per thread (D=1024).
// ---------------------------------------------------------------------------
__global__ __launch_bounds__(256)
void ln_kernel(const float* __restrict__ x, const float* __restrict__ g,
               const float* __restrict__ b, float* __restrict__ y) {
  const int row = blockIdx.x;
  const int t = threadIdx.x;
  const float* xr = x + (size_t)row * DMODEL;
  float4 v = *(const float4*)(xr + t * 4);
  float s = v.x + v.y + v.z + v.w;
  float q = v.x * v.x + v.y * v.y + v.z * v.z + v.w * v.w;
  #pragma unroll
  for (int off = 32; off; off >>= 1) {
    s += __shfl_xor(s, off);
    q += __shfl_xor(q, off);
  }
  __shared__ float ss[4], qq[4];
  if ((t & 63) == 0) { ss[t >> 6] = s; qq[t >> 6] = q; }
  __syncthreads();
  s = ss[0] + ss[1] + ss[2] + ss[3];
  q = qq[0] + qq[1] + qq[2] + qq[3];
  const float mean = s * (1.f / DMODEL);
  const float var = q * (1.f / DMODEL) - mean * mean;
  const float rstd = rsqrtf(var + 1e-5f);
  float4 gv = *(const float4*)(g + t * 4);
  float4 bv = *(const float4*)(b + t * 4);
  float4 o;
  o.x = (v.x - mean) * rstd * gv.x + bv.x;
  o.y = (v.y - mean) * rstd * gv.y + bv.y;
  o.z = (v.z - mean) * rstd * gv.z + bv.z;
  o.w = (v.w - mean) * rstd * gv.w + bv.w;
  *(float4*)(y + (size_t)row * DMODEL + t * 4) = o;
}

// ---------------------------------------------------------------------------
// GELU (GPT-2 'gelu_new'): 0.5*x*(1+tanh(sqrt(2/pi)*(x+0.044715*x^3)))
// tanh(u) = 1 - 2/(exp(2u)+1); saturates correctly at +/-inf.
// ---------------------------------------------------------------------------
__device__ __forceinline__ float gelu_new_f(float x) {
  const float c = 0.7978845608028654f;  // sqrt(2/pi)
  float u = c * (x + 0.044715f * x * x * x);
  float e = __expf(2.f * u);
  float t = 1.f - 2.f / (e + 1.f);
  return 0.5f * x * (1.f + t);
}

// ---------------------------------------------------------------------------
// fp32 GEMM: C[M,N] = A[M,K] @ B[K,N] + bias[N] (+ R[M,N]) (gelu optional)
// Tile 128x128xBK8, 256 threads, 8x8 micro-tile as 2x2 blocks of 4x4 at
// offsets {0,64} (keeps LDS reads <=2-way conflicted = free).
// ---------------------------------------------------------------------------
template <bool GELU, bool RES>
__global__ __launch_bounds__(256)
void gemm_kernel(const float* __restrict__ A, const float* __restrict__ B,
                 const float* __restrict__ bias, const float* __restrict__ R,
                 float* __restrict__ C, int M, int N, int K) {
  __shared__ float As[8][128];
  __shared__ float Bs[8][128];
  const int t = threadIdx.x;
  const int bn = blockIdx.x, bm = blockIdx.y;
  const int tx = t & 15, ty = t >> 4;
  const int arow = t >> 1, ac4 = (t & 1) * 4;
  const int brow = t >> 5, bc4 = (t & 31) * 4;
  const float* Ap = A + (size_t)(bm * 128 + arow) * K + ac4;
  const float* Bp = B + (size_t)brow * N + bn * 128 + bc4;

  float4 pa = *(const float4*)Ap;
  float4 pb = *(const float4*)Bp;

  float acc[8][8];
  #pragma unroll
  for (int i = 0; i < 8; ++i)
    #pragma unroll
    for (int j = 0; j < 8; ++j) acc[i][j] = 0.f;

  const int KT = K >> 3;
  for (int kt = 0; kt < KT; ++kt) {
    __syncthreads();
    As[ac4 + 0][arow] = pa.x;
    As[ac4 + 1][arow] = pa.y;
    As[ac4 + 2][arow] = pa.z;
    As[ac4 + 3][arow] = pa.w;
    *(float4*)&Bs[brow][bc4] = pb;
    __syncthreads();
    if (kt + 1 < KT) {
      pa = *(const float4*)(Ap + (kt + 1) * 8);
      pb = *(const float4*)(Bp + (size_t)(kt + 1) * 8 * N);
    }
    #pragma unroll
    for (int k = 0; k < 8; ++k) {
      float4 a0 = *(const float4*)&As[k][ty * 4];
      float4 a1 = *(const float4*)&As[k][64 + ty * 4];
      float4 b0 = *(const float4*)&Bs[k][tx * 4];
      float4 b1 = *(const float4*)&Bs[k][64 + tx * 4];
      float av[8] = {a0.x, a0.y, a0.z, a0.w, a1.x, a1.y, a1.z, a1.w};
      float bv[8] = {b0.x, b0.y, b0.z, b0.w, b1.x, b1.y, b1.z, b1.w};
      #pragma unroll
      for (int i = 0; i < 8; ++i)
        #pragma unroll
        for (int j = 0; j < 8; ++j)
          acc[i][j] = fmaf(av[i], bv[j], acc[i][j]);
    }
  }

  const int ccol0 = bn * 128 + tx * 4;
  float4 bias0 = *(const float4*)(bias + ccol0);
  float4 bias1 = *(const float4*)(bias + ccol0 + 64);
  #pragma unroll
  for (int i = 0; i < 8; ++i) {
    const int ro = (i < 4) ? (ty * 4 + i) : (64 + ty * 4 + (i - 4));
    const size_t row = (size_t)(bm * 128 + ro);
    float v[8];
    v[0] = acc[i][0] + bias0.x; v[1] = acc[i][1] + bias0.y;
    v[2] = acc[i][2] + bias0.z; v[3] = acc[i][3] + bias0.w;
    v[4] = acc[i][4] + bias1.x; v[5] = acc[i][5] + bias1.y;
    v[6] = acc[i][6] + bias1.z; v[7] = acc[i][7] + bias1.w;
    if (GELU) {
      #pragma unroll
      for (int j = 0; j < 8; ++j) v[j] = gelu_new_f(v[j]);
    }
    if (RES) {
      float4 r0 = *(const float4*)(R + row * N + ccol0);
      float4 r1 = *(const float4*)(R + row * N + ccol0 + 64);
      v[0] += r0.x; v[1] += r0.y; v[2] += r0.z; v[3] += r0.w;
      v[4] += r1.x; v[5] += r1.y; v[6] += r1.z; v[7] += r1.w;
    }
    float4 o0 = {v[0], v[1], v[2], v[3]};
    float4 o1 = {v[4], v[5], v[6], v[7]};
    *(float4*)(C + row * N + ccol0) = o0;
    *(float4*)(C + row * N + ccol0 + 64) = o1;
  }
}

// ---------------------------------------------------------------------------
// Causal flash attention, fp32. qkv[M,3D] packed; out[M,D].
// Block = one (b,h,q-tile of 64). 4 waves x 16 query rows each.
// QK^T: lane=key, K-row preloaded to regs, Q read as LDS broadcast.
// PV:   lane=dim, V-col preloaded to regs, P read as LDS broadcast.
// Online softmax per row via 64-lane shfl reductions. Mask value -10000.0f
// matches the reference (exp underflows to 0 identically).
// ---------------------------------------------------------------------------
__global__ __launch_bounds__(256)
void attn_kernel(const float* __restrict__ qkv, float* __restrict__ out) {
  const int qt = blockIdx.x, h = blockIdx.y, b = blockIdx.z;
  const int t = threadIdx.x, lane = t & 63, w = t >> 6;
  __shared__ float Qs[64][68];
  __shared__ float Ks[64][68];
  __shared__ float Vs[64][68];
  __shared__ float Ps[4][16][64];
  const int q0 = qt * 64;
  const float* base = qkv + (size_t)b * SEQ * (3 * DMODEL);

  // load Q tile, pre-scaled by 1/sqrt(DH)=0.125
  #pragma unroll
  for (int i = 0; i < 4; ++i) {
    int idx = t + i * 256;
    int r = idx >> 4, c4 = (idx & 15) << 2;
    float4 qv = *(const float4*)(base + (size_t)(q0 + r) * 3072 + h * 64 + c4);
    float4 sv = {qv.x * 0.125f, qv.y * 0.125f, qv.z * 0.125f, qv.w * 0.125f};
    *(float4*)&Qs[r][c4] = sv;
  }

  float m_r[16], l_r[16], o_r[16];
  #pragma unroll
  for (int r = 0; r < 16; ++r) { m_r[r] = -1e30f; l_r[r] = 0.f; o_r[r] = 0.f; }

  for (int kt = 0; kt <= qt; ++kt) {
    const int k0 = kt * 64;
    __syncthreads();  // previous tile's reg-preloads done before overwrite
    #pragma unroll
    for (int i = 0; i < 4; ++i) {
      int idx = t + i * 256;
      int r = idx >> 4, c4 = (idx & 15) << 2;
      *(float4*)&Ks[r][c4] =
          *(const float4*)(base + (size_t)(k0 + r) * 3072 + 1024 + h * 64 + c4);
      *(float4*)&Vs[r][c4] =
          *(const float4*)(base + (size_t)(k0 + r) * 3072 + 2048 + h * 64 + c4);
    }
    __syncthreads();

    float reg[64];  // K row (QK phase), then reused as V column (PV phase)
    #pragma unroll
    for (int i = 0; i < 16; ++i) {
      float4 kv = *(const float4*)&Ks[lane][i * 4];
      reg[i * 4 + 0] = kv.x; reg[i * 4 + 1] = kv.y;
      reg[i * 4 + 2] = kv.z; reg[i * 4 + 3] = kv.w;
    }
    const bool diag = (kt == qt);
    #pragma unroll
    for (int r = 0; r < 16; ++r) {
      const int qrow = q0 + (w << 4) + r;
      float s = 0.f;
      #pragma unroll
      for (int i = 0; i < 16; ++i) {
        float4 qv = *(const float4*)&Qs[(w << 4) + r][i * 4];
        s = fmaf(qv.x, reg[i * 4 + 0], s);
        s = fmaf(qv.y, reg[i * 4 + 1], s);
        s = fmaf(qv.z, reg[i * 4 + 2], s);
        s = fmaf(qv.w, reg[i * 4 + 3], s);
      }
      if (diag && (k0 + lane > qrow)) s = -10000.0f;
      float mt = s;
      #pragma unroll
      for (int off = 32; off; off >>= 1) mt = fmaxf(mt, __shfl_xor(mt, off));
      const float mn = fmaxf(m_r[r], mt);
      const float p = __expf(s - mn);
      float ps = p;
      #pragma unroll
      for (int off = 32; off; off >>= 1) ps += __shfl_xor(ps, off);
      const float sc = __expf(m_r[r] - mn);
      l_r[r] = l_r[r] * sc + ps;
      o_r[r] *= sc;
      m_r[r] = mn;
      Ps[w][r][lane] = p;
    }
    #pragma unroll
    for (int j = 0; j < 64; ++j) reg[j] = Vs[j][lane];
    #pragma unroll
    for (int r = 0; r < 16; ++r) {
      float acc = 0.f;
      #pragma unroll
      for (int i = 0; i < 16; ++i) {
        float4 pv = *(const float4*)&Ps[w][r][i * 4];
        acc = fmaf(pv.x, reg[i * 4 + 0], acc);
        acc = fmaf(pv.y, reg[i * 4 + 1], acc);
        acc = fmaf(pv.z, reg[i * 4 + 2], acc);
        acc = fmaf(pv.w, reg[i * 4 + 3], acc);
      }
      o_r[r] += acc;
    }
  }
  #pragma unroll
  for (int r = 0; r < 16; ++r) {
    out[((size_t)(b * SEQ + q0 + (w << 4) + r)) * DMODEL + h * 64 + lane] =
        o_r[r] / l_r[r];
  }
}

// ---------------------------------------------------------------------------
// Launcher
// ---------------------------------------------------------------------------
extern "C" void kernel_launch(void* const* d_in, const int* in_sizes, int n_in,
                              void* d_out, int out_size, void* d_ws, size_t ws_size,
                              hipStream_t stream) {
  const float* hidden      = (const float*)d_in[0];
  const float* ln1_g       = (const float*)d_in[1];
  const float* ln1_b       = (const float*)d_in[2];
  const float* w_attn      = (const float*)d_in[3];
  const float* b_attn      = (const float*)d_in[4];
  const float* w_attn_proj = (const float*)d_in[5];
  const float* b_attn_proj = (const float*)d_in[6];
  const float* ln2_g       = (const float*)d_in[7];
  const float* ln2_b       = (const float*)d_in[8];
  const float* w_fc        = (const float*)d_in[9];
  const float* b_fc        = (const float*)d_in[10];
  const float* w_mlp_proj  = (const float*)d_in[11];
  const float* b_mlp_proj  = (const float*)d_in[12];
  float* out = (float*)d_out;

  const int Bn = in_sizes[0] / (SEQ * DMODEL);  // batch (=4)
  const int M = Bn * SEQ;                        // 8192 rows

  // Workspace layout (floats). Total = 58,720,256 floats = 235 MB.
  float* ws = (float*)d_ws;
  float* xln      = ws;                                   // M*D      (LN1, reused for LN2)
  float* qkv_a1   = ws + (size_t)M * DMODEL;              // max(M*3D, M*FF) = M*FF
  float* attn_out = qkv_a1 + (size_t)M * FFDIM;           // M*D
  float* h2       = attn_out + (size_t)M * DMODEL;        // M*D

  // 1. LN1
  ln_kernel<<<M, 256, 0, stream>>>(hidden, ln1_g, ln1_b, xln);
  // 2. QKV = xln @ w_attn + b_attn       [M,3072]
  gemm_kernel<false, false><<<dim3(3 * DMODEL / 128, M / 128), 256, 0, stream>>>(
      xln, w_attn, b_attn, nullptr, qkv_a1, M, 3 * DMODEL, DMODEL);
  // 3. attention -> attn_out [M,1024]
  attn_kernel<<<dim3(SEQ / 64, NHEAD, Bn), 256, 0, stream>>>(qkv_a1, attn_out);
  // 4. h2 = hidden + attn_out @ w_attn_proj + b
  gemm_kernel<false, true><<<dim3(DMODEL / 128, M / 128), 256, 0, stream>>>(
      attn_out, w_attn_proj, b_attn_proj, hidden, h2, M, DMODEL, DMODEL);
  // 5. LN2
  ln_kernel<<<M, 256, 0, stream>>>(h2, ln2_g, ln2_b, xln);
  // 6. a1 = gelu(xln @ w_fc + b_fc)      [M,4096]
  gemm_kernel<true, false><<<dim3(FFDIM / 128, M / 128), 256, 0, stream>>>(
      xln, w_fc, b_fc, nullptr, qkv_a1, M, FFDIM, DMODEL);
  // 7. out = h2 + a1 @ w_mlp_proj + b
  gemm_kernel<false, true><<<dim3(DMODEL / 128, M / 128), 256, 0, stream>>>(
      qkv_a1, w_mlp_proj, b_mlp_proj, h2, out, M, DMODEL, FFDIM);
}

// Round 3
// 2564.831 us; speedup vs baseline: 3.4645x; 3.4645x over previous
//
#include <hip/hip_runtime.h>
#include <hip/hip_bf16.h>
#include <cstddef>

// GPT-2 block. B=4 (derived), S=2048, D=1024, H=16, DH=64, FF=4096.
#define SEQ   2048
#define DMODEL 1024
#define NHEAD 16
#define HDIM  64
#define FFDIM 4096

typedef __attribute__((ext_vector_type(8))) short bf16x8;
typedef __attribute__((ext_vector_type(4))) float f32x4;

__device__ __forceinline__ unsigned short f2b(float x) {
  __hip_bfloat16 h = __float2bfloat16(x);
  return __builtin_bit_cast(unsigned short, h);
}

// ---------------------------------------------------------------------------
// LayerNorm: one block per row, 256 threads, float4 per thread (D=1024).
// ---------------------------------------------------------------------------
__global__ __launch_bounds__(256)
void ln_kernel(const float* __restrict__ x, const float* __restrict__ g,
               const float* __restrict__ b, float* __restrict__ y) {
  const int row = blockIdx.x;
  const int t = threadIdx.x;
  const float* xr = x + (size_t)row * DMODEL;
  float4 v = *(const float4*)(xr + t * 4);
  float s = v.x + v.y + v.z + v.w;
  float q = v.x * v.x + v.y * v.y + v.z * v.z + v.w * v.w;
  #pragma unroll
  for (int off = 32; off; off >>= 1) {
    s += __shfl_xor(s, off);
    q += __shfl_xor(q, off);
  }
  __shared__ float ss[4], qq[4];
  if ((t & 63) == 0) { ss[t >> 6] = s; qq[t >> 6] = q; }
  __syncthreads();
  s = ss[0] + ss[1] + ss[2] + ss[3];
  q = qq[0] + qq[1] + qq[2] + qq[3];
  const float mean = s * (1.f / DMODEL);
  const float var = q * (1.f / DMODEL) - mean * mean;
  const float rstd = rsqrtf(var + 1e-5f);
  float4 gv = *(const float4*)(g + t * 4);
  float4 bv = *(const float4*)(b + t * 4);
  float4 o;
  o.x = (v.x - mean) * rstd * gv.x + bv.x;
  o.y = (v.y - mean) * rstd * gv.y + bv.y;
  o.z = (v.z - mean) * rstd * gv.z + bv.z;
  o.w = (v.w - mean) * rstd * gv.w + bv.w;
  *(float4*)(y + (size_t)row * DMODEL + t * 4) = o;
}

// ---------------------------------------------------------------------------
// GELU (GPT-2 'gelu_new')
// ---------------------------------------------------------------------------
__device__ __forceinline__ float gelu_new_f(float x) {
  const float c = 0.7978845608028654f;  // sqrt(2/pi)
  float u = c * (x + 0.044715f * x * x * x);
  float e = __expf(2.f * u);
  float t = 1.f - 2.f / (e + 1.f);
  return 0.5f * x * (1.f + t);
}

// ---------------------------------------------------------------------------
// fp32 GEMM: C[M,N] = A[M,K] @ B[K,N] + bias[N] (+ R[M,N]) (gelu optional)
// ---------------------------------------------------------------------------
template <bool GELU, bool RES>
__global__ __launch_bounds__(256)
void gemm_kernel(const float* __restrict__ A, const float* __restrict__ B,
                 const float* __restrict__ bias, const float* __restrict__ R,
                 float* __restrict__ C, int M, int N, int K) {
  __shared__ float As[8][128];
  __shared__ float Bs[8][128];
  const int t = threadIdx.x;
  const int bn = blockIdx.x, bm = blockIdx.y;
  const int tx = t & 15, ty = t >> 4;
  const int arow = t >> 1, ac4 = (t & 1) * 4;
  const int brow = t >> 5, bc4 = (t & 31) * 4;
  const float* Ap = A + (size_t)(bm * 128 + arow) * K + ac4;
  const float* Bp = B + (size_t)brow * N + bn * 128 + bc4;

  float4 pa = *(const float4*)Ap;
  float4 pb = *(const float4*)Bp;

  float acc[8][8];
  #pragma unroll
  for (int i = 0; i < 8; ++i)
    #pragma unroll
    for (int j = 0; j < 8; ++j) acc[i][j] = 0.f;

  const int KT = K >> 3;
  for (int kt = 0; kt < KT; ++kt) {
    __syncthreads();
    As[ac4 + 0][arow] = pa.x;
    As[ac4 + 1][arow] = pa.y;
    As[ac4 + 2][arow] = pa.z;
    As[ac4 + 3][arow] = pa.w;
    *(float4*)&Bs[brow][bc4] = pb;
    __syncthreads();
    if (kt + 1 < KT) {
      pa = *(const float4*)(Ap + (kt + 1) * 8);
      pb = *(const float4*)(Bp + (size_t)(kt + 1) * 8 * N);
    }
    #pragma unroll
    for (int k = 0; k < 8; ++k) {
      float4 a0 = *(const float4*)&As[k][ty * 4];
      float4 a1 = *(const float4*)&As[k][64 + ty * 4];
      float4 b0 = *(const float4*)&Bs[k][tx * 4];
      float4 b1 = *(const float4*)&Bs[k][64 + tx * 4];
      float av[8] = {a0.x, a0.y, a0.z, a0.w, a1.x, a1.y, a1.z, a1.w};
      float bv[8] = {b0.x, b0.y, b0.z, b0.w, b1.x, b1.y, b1.z, b1.w};
      #pragma unroll
      for (int i = 0; i < 8; ++i)
        #pragma unroll
        for (int j = 0; j < 8; ++j)
          acc[i][j] = fmaf(av[i], bv[j], acc[i][j]);
    }
  }

  const int ccol0 = bn * 128 + tx * 4;
  float4 bias0 = *(const float4*)(bias + ccol0);
  float4 bias1 = *(const float4*)(bias + ccol0 + 64);
  #pragma unroll
  for (int i = 0; i < 8; ++i) {
    const int ro = (i < 4) ? (ty * 4 + i) : (64 + ty * 4 + (i - 4));
    const size_t row = (size_t)(bm * 128 + ro);
    float v[8];
    v[0] = acc[i][0] + bias0.x; v[1] = acc[i][1] + bias0.y;
    v[2] = acc[i][2] + bias0.z; v[3] = acc[i][3] + bias0.w;
    v[4] = acc[i][4] + bias1.x; v[5] = acc[i][5] + bias1.y;
    v[6] = acc[i][6] + bias1.z; v[7] = acc[i][7] + bias1.w;
    if (GELU) {
      #pragma unroll
      for (int j = 0; j < 8; ++j) v[j] = gelu_new_f(v[j]);
    }
    if (RES) {
      float4 r0 = *(const float4*)(R + row * N + ccol0);
      float4 r1 = *(const float4*)(R + row * N + ccol0 + 64);
      v[0] += r0.x; v[1] += r0.y; v[2] += r0.z; v[3] += r0.w;
      v[4] += r1.x; v[5] += r1.y; v[6] += r1.z; v[7] += r1.w;
    }
    float4 o0 = {v[0], v[1], v[2], v[3]};
    float4 o1 = {v[4], v[5], v[6], v[7]};
    *(float4*)(C + row * N + ccol0) = o0;
    *(float4*)(C + row * N + ccol0 + 64) = o1;
  }
}

// ---------------------------------------------------------------------------
// Prep: qkv fp32 [b][s][3*D] -> Qb (x0.125), Kb bf16 [b][h][s][64],
//       Vtb bf16 [b][h][64][s]  (V transposed via LDS tile)
// ---------------------------------------------------------------------------
__global__ __launch_bounds__(256)
void prep_kernel(const float* __restrict__ qkv, short* __restrict__ Qb,
                 short* __restrict__ Kb, short* __restrict__ Vtb) {
  const int st = blockIdx.x, h = blockIdx.y, b = blockIdx.z;
  const int t = threadIdx.x;
  const int s0 = st * 64;
  const size_t bh = (size_t)b * NHEAD + h;
  __shared__ short vt[64][72];
  #pragma unroll
  for (int i = 0; i < 2; ++i) {
    const int cc = t + i * 256;
    const int r = cc >> 3, d8 = (cc & 7) * 8;
    const float* src = qkv + ((size_t)b * SEQ + s0 + r) * 3072 + h * 64 + d8;
    float4 a0 = *(const float4*)(src);
    float4 a1 = *(const float4*)(src + 4);
    bf16x8 q8;
    q8[0] = (short)f2b(a0.x * 0.125f); q8[1] = (short)f2b(a0.y * 0.125f);
    q8[2] = (short)f2b(a0.z * 0.125f); q8[3] = (short)f2b(a0.w * 0.125f);
    q8[4] = (short)f2b(a1.x * 0.125f); q8[5] = (short)f2b(a1.y * 0.125f);
    q8[6] = (short)f2b(a1.z * 0.125f); q8[7] = (short)f2b(a1.w * 0.125f);
    *(bf16x8*)(Qb + (bh * SEQ + s0 + r) * 64 + d8) = q8;
    float4 k0 = *(const float4*)(src + 1024);
    float4 k1 = *(const float4*)(src + 1028);
    bf16x8 k8;
    k8[0] = (short)f2b(k0.x); k8[1] = (short)f2b(k0.y);
    k8[2] = (short)f2b(k0.z); k8[3] = (short)f2b(k0.w);
    k8[4] = (short)f2b(k1.x); k8[5] = (short)f2b(k1.y);
    k8[6] = (short)f2b(k1.z); k8[7] = (short)f2b(k1.w);
    *(bf16x8*)(Kb + (bh * SEQ + s0 + r) * 64 + d8) = k8;
    float4 v0 = *(const float4*)(src + 2048);
    float4 v1 = *(const float4*)(src + 2052);
    vt[d8 + 0][r] = (short)f2b(v0.x); vt[d8 + 1][r] = (short)f2b(v0.y);
    vt[d8 + 2][r] = (short)f2b(v0.z); vt[d8 + 3][r] = (short)f2b(v0.w);
    vt[d8 + 4][r] = (short)f2b(v1.x); vt[d8 + 5][r] = (short)f2b(v1.y);
    vt[d8 + 6][r] = (short)f2b(v1.z); vt[d8 + 7][r] = (short)f2b(v1.w);
  }
  __syncthreads();
  #pragma unroll
  for (int i = 0; i < 2; ++i) {
    const int cc = t + i * 256;
    const int d = cc >> 3, s8 = (cc & 7) * 8;
    bf16x8 vv;
    #pragma unroll
    for (int j = 0; j < 8; ++j) vv[j] = vt[d][s8 + j];
    *(bf16x8*)(Vtb + (bh * 64 + d) * SEQ + s0 + s8) = vv;
  }
}

// ---------------------------------------------------------------------------
// bf16 MFMA causal flash attention.
// Block = (q-tile 64, h, b); 4 waves x 16 q-rows. mfma_f32_16x16x32_bf16.
// Swapped QK^T: S^T tile per MFMA has row=key=(g*4+reg), col=q=lane&15.
// K/Vt staged in LDS with XOR swizzle byte^=((row&7)<<4); P via per-wave
// swizzled LDS to re-fragment for PV. Q (pre-scaled 0.125) in registers.
// ---------------------------------------------------------------------------
__global__ __launch_bounds__(256)
void mha_kernel(const short* __restrict__ Qb, const short* __restrict__ Kb,
                const short* __restrict__ Vtb, float* __restrict__ out) {
  const int qt = blockIdx.x, h = blockIdx.y, b = blockIdx.z;
  const int t = threadIdx.x, lane = t & 63, w = t >> 6;
  const int g = lane >> 4, la = lane & 15;
  const size_t bh = (size_t)b * NHEAD + h;

  __shared__ short Ks[64 * 64];
  __shared__ short Vts[64 * 64];
  __shared__ short Ps[4][16 * 64];

  const short* qrow = Qb + (bh * SEQ + (size_t)qt * 64 + w * 16 + la) * 64;
  const bf16x8 qf0 = *(const bf16x8*)(qrow + g * 8);
  const bf16x8 qf1 = *(const bf16x8*)(qrow + 32 + g * 8);

  float o[16];
  #pragma unroll
  for (int i = 0; i < 16; ++i) o[i] = 0.f;
  float m = -1e30f, l = 0.f;

  const int sr0 = t >> 3, sc8 = (t & 7) * 8;

  for (int kt = 0; kt <= qt; ++kt) {
    const int k0 = kt * 64;
    __syncthreads();
    #pragma unroll
    for (int i = 0; i < 2; ++i) {
      const int r = sr0 + i * 32;
      bf16x8 kv = *(const bf16x8*)(Kb + (bh * SEQ + k0 + r) * 64 + sc8);
      bf16x8 vv = *(const bf16x8*)(Vtb + (bh * 64 + r) * SEQ + k0 + sc8);
      const int lb = r * 128 + ((sc8 * 2) ^ ((r & 7) << 4));
      *(bf16x8*)((char*)Ks + lb) = kv;
      *(bf16x8*)((char*)Vts + lb) = vv;
    }
    __syncthreads();

    float sv[16];
    #pragma unroll
    for (int mt = 0; mt < 4; ++mt) {
      const int ar = mt * 16 + la;
      const int ab = ar * 128 + ((g * 16) ^ ((ar & 7) << 4));
      bf16x8 ka0 = *(const bf16x8*)((char*)Ks + ab);
      bf16x8 ka1 = *(const bf16x8*)((char*)Ks + (ab ^ 64));
      f32x4 sa = {0.f, 0.f, 0.f, 0.f};
      sa = __builtin_amdgcn_mfma_f32_16x16x32_bf16(ka0, qf0, sa, 0, 0, 0);
      sa = __builtin_amdgcn_mfma_f32_16x16x32_bf16(ka1, qf1, sa, 0, 0, 0);
      sv[mt * 4 + 0] = sa[0]; sv[mt * 4 + 1] = sa[1];
      sv[mt * 4 + 2] = sa[2]; sv[mt * 4 + 3] = sa[3];
    }

    if (kt == qt) {  // causal mask on the diagonal tile (exact -10000 match)
      const int qrel = w * 16 + la;
      #pragma unroll
      for (int idx = 0; idx < 16; ++idx) {
        const int krel = (idx >> 2) * 16 + g * 4 + (idx & 3);
        if (krel > qrel) sv[idx] = -10000.0f;
      }
    }

    float tmax = sv[0];
    #pragma unroll
    for (int i = 1; i < 16; ++i) tmax = fmaxf(tmax, sv[i]);
    tmax = fmaxf(tmax, __shfl_xor(tmax, 16));
    tmax = fmaxf(tmax, __shfl_xor(tmax, 32));
    const float mn = fmaxf(m, tmax);
    const float sc = __expf(m - mn);
    m = mn;
    float ps = 0.f;
    #pragma unroll
    for (int i = 0; i < 16; ++i) { sv[i] = __expf(sv[i] - mn); ps += sv[i]; }
    ps += __shfl_xor(ps, 16);
    ps += __shfl_xor(ps, 32);
    l = l * sc + ps;
    // O lives as q=(g*4+reg): fetch this lane's scale factors cross-lane
    #pragma unroll
    for (int r = 0; r < 4; ++r) {
      const float scr = __shfl(sc, (g << 2) + r);
      o[r] *= scr; o[4 + r] *= scr; o[8 + r] *= scr; o[12 + r] *= scr;
    }
    // write P (bf16) to per-wave swizzled LDS
    #pragma unroll
    for (int mt = 0; mt < 4; ++mt) {
      #pragma unroll
      for (int r2 = 0; r2 < 2; ++r2) {
        const unsigned pk = (unsigned)f2b(sv[mt * 4 + r2 * 2]) |
                            ((unsigned)f2b(sv[mt * 4 + r2 * 2 + 1]) << 16);
        const int kk = mt * 16 + g * 4 + r2 * 2;
        const int pb = la * 128 + ((kk * 2) ^ ((la & 7) << 4));
        *(unsigned*)((char*)Ps[w] + pb) = pk;
      }
    }
    // same-wave cross-lane LDS RAW hazard: drain + pin (rule #18)
    asm volatile("s_waitcnt lgkmcnt(0)" ::: "memory");
    __builtin_amdgcn_sched_barrier(0);

    const int pb0 = la * 128 + ((g * 16) ^ ((la & 7) << 4));
    const bf16x8 pa0 = *(const bf16x8*)((char*)Ps[w] + pb0);
    const bf16x8 pa1 = *(const bf16x8*)((char*)Ps[w] + (pb0 ^ 64));
    #pragma unroll
    for (int nt = 0; nt < 4; ++nt) {
      const int dr = nt * 16 + la;
      const int vb = dr * 128 + ((g * 16) ^ ((dr & 7) << 4));
      bf16x8 vb0 = *(const bf16x8*)((char*)Vts + vb);
      bf16x8 vb1 = *(const bf16x8*)((char*)Vts + (vb ^ 64));
      f32x4 oa = {o[nt * 4 + 0], o[nt * 4 + 1], o[nt * 4 + 2], o[nt * 4 + 3]};
      oa = __builtin_amdgcn_mfma_f32_16x16x32_bf16(pa0, vb0, oa, 0, 0, 0);
      oa = __builtin_amdgcn_mfma_f32_16x16x32_bf16(pa1, vb1, oa, 0, 0, 0);
      o[nt * 4 + 0] = oa[0]; o[nt * 4 + 1] = oa[1];
      o[nt * 4 + 2] = oa[2]; o[nt * 4 + 3] = oa[3];
    }
  }

  const float linv = 1.f / l;
  #pragma unroll
  for (int r = 0; r < 4; ++r) {
    const float li = __shfl(linv, (g << 2) + r);
    const int qrow_g = qt * 64 + w * 16 + g * 4 + r;
    #pragma unroll
    for (int nt = 0; nt < 4; ++nt) {
      out[((size_t)b * SEQ + qrow_g) * DMODEL + h * 64 + nt * 16 + la] =
          o[nt * 4 + r] * li;
    }
  }
}

// ---------------------------------------------------------------------------
// Launcher
// ---------------------------------------------------------------------------
extern "C" void kernel_launch(void* const* d_in, const int* in_sizes, int n_in,
                              void* d_out, int out_size, void* d_ws, size_t ws_size,
                              hipStream_t stream) {
  const float* hidden      = (const float*)d_in[0];
  const float* ln1_g       = (const float*)d_in[1];
  const float* ln1_b       = (const float*)d_in[2];
  const float* w_attn      = (const float*)d_in[3];
  const float* b_attn      = (const float*)d_in[4];
  const float* w_attn_proj = (const float*)d_in[5];
  const float* b_attn_proj = (const float*)d_in[6];
  const float* ln2_g       = (const float*)d_in[7];
  const float* ln2_b       = (const float*)d_in[8];
  const float* w_fc        = (const float*)d_in[9];
  const float* b_fc        = (const float*)d_in[10];
  const float* w_mlp_proj  = (const float*)d_in[11];
  const float* b_mlp_proj  = (const float*)d_in[12];
  float* out = (float*)d_out;

  const int Bn = in_sizes[0] / (SEQ * DMODEL);  // batch (=4)
  const int M = Bn * SEQ;                        // 8192 rows

  // Workspace layout (floats), 235 MB total:
  //   xln      [0,        M*D)    fp32 LN out; REUSED as Qb+Kb bf16 during attn
  //   qkv_a1   [M*D,      +M*FF)  qkv fp32, later FF activations
  //   attn_out [.., +M*D)         attention result fp32
  //   h2       [.., +M*D)         residual-1; REUSED as Vtb bf16 during attn
  float* ws = (float*)d_ws;
  float* xln      = ws;
  float* qkv_a1   = ws + (size_t)M * DMODEL;
  float* attn_out = qkv_a1 + (size_t)M * FFDIM;
  float* h2       = attn_out + (size_t)M * DMODEL;

  short* Qb  = (short*)xln;                       // M*64*H shorts = 16.8MB
  short* Kb  = Qb + (size_t)M * DMODEL;           // next 16.8MB (fits in xln's 33.5MB)
  short* Vtb = (short*)h2;                        // 16.8MB in h2's 33.5MB

  // 1. LN1
  ln_kernel<<<M, 256, 0, stream>>>(hidden, ln1_g, ln1_b, xln);
  // 2. QKV = xln @ w_attn + b_attn       [M,3072]
  gemm_kernel<false, false><<<dim3(3 * DMODEL / 128, M / 128), 256, 0, stream>>>(
      xln, w_attn, b_attn, nullptr, qkv_a1, M, 3 * DMODEL, DMODEL);
  // 2.5 convert to bf16 Q/K + transposed V (xln dead from here until step 5)
  prep_kernel<<<dim3(SEQ / 64, NHEAD, Bn), 256, 0, stream>>>(qkv_a1, Qb, Kb, Vtb);
  // 3. attention -> attn_out [M,1024]
  mha_kernel<<<dim3(SEQ / 64, NHEAD, Bn), 256, 0, stream>>>(Qb, Kb, Vtb, attn_out);
  // 4. h2 = hidden + attn_out @ w_attn_proj + b   (overwrites Vtb - dead)
  gemm_kernel<false, true><<<dim3(DMODEL / 128, M / 128), 256, 0, stream>>>(
      attn_out, w_attn_proj, b_attn_proj, hidden, h2, M, DMODEL, DMODEL);
  // 5. LN2 (overwrites Qb/Kb - dead)
  ln_kernel<<<M, 256, 0, stream>>>(h2, ln2_g, ln2_b, xln);
  // 6. a1 = gelu(xln @ w_fc + b_fc)      [M,4096]
  gemm_kernel<true, false><<<dim3(FFDIM / 128, M / 128), 256, 0, stream>>>(
      xln, w_fc, b_fc, nullptr, qkv_a1, M, FFDIM, DMODEL);
  // 7. out = h2 + a1 @ w_mlp_proj + b
  gemm_kernel<false, true><<<dim3(DMODEL / 128, M / 128), 256, 0, stream>>>(
      qkv_a1, w_mlp_proj, b_mlp_proj, h2, out, M, DMODEL, FFDIM);
}

// Round 4
// 618.612 us; speedup vs baseline: 14.3643x; 4.1461x over previous
//
#include <hip/hip_runtime.h>
#include <hip/hip_bf16.h>
#include <cstddef>

// GPT-2 block. B=4 (derived), S=2048, D=1024, H=16, DH=64, FF=4096.
#define SEQ   2048
#define DMODEL 1024
#define NHEAD 16
#define HDIM  64
#define FFDIM 4096

typedef __attribute__((ext_vector_type(8))) short bf16x8;
typedef __attribute__((ext_vector_type(4))) short bf16x4;
typedef __attribute__((ext_vector_type(4))) float f32x4;

__device__ __forceinline__ unsigned short f2b(float x) {
  __hip_bfloat16 h = __float2bfloat16(x);
  return __builtin_bit_cast(unsigned short, h);
}
__device__ __forceinline__ float b2f(short u) {
  unsigned x = ((unsigned)(unsigned short)u) << 16;
  return __builtin_bit_cast(float, x);
}
// async global->LDS, 16B per lane. LDS dest = wave-uniform base + lane*16.
__device__ __forceinline__ void gl16(const short* g, short* l) {
  __builtin_amdgcn_global_load_lds(
      (const __attribute__((address_space(1))) void*)g,
      (__attribute__((address_space(3))) void*)l, 16, 0, 0);
}

// ---------------------------------------------------------------------------
// LayerNorm: one block per row, 256 threads, float4/thread; bf16 output.
// ---------------------------------------------------------------------------
__global__ __launch_bounds__(256)
void ln_kernel(const float* __restrict__ x, const float* __restrict__ g,
               const float* __restrict__ b, short* __restrict__ y) {
  const int row = blockIdx.x;
  const int t = threadIdx.x;
  const float* xr = x + (size_t)row * DMODEL;
  float4 v = *(const float4*)(xr + t * 4);
  float s = v.x + v.y + v.z + v.w;
  float q = v.x * v.x + v.y * v.y + v.z * v.z + v.w * v.w;
  #pragma unroll
  for (int off = 32; off; off >>= 1) {
    s += __shfl_xor(s, off);
    q += __shfl_xor(q, off);
  }
  __shared__ float ss[4], qq[4];
  if ((t & 63) == 0) { ss[t >> 6] = s; qq[t >> 6] = q; }
  __syncthreads();
  s = ss[0] + ss[1] + ss[2] + ss[3];
  q = qq[0] + qq[1] + qq[2] + qq[3];
  const float mean = s * (1.f / DMODEL);
  const float var = q * (1.f / DMODEL) - mean * mean;
  const float rstd = rsqrtf(var + 1e-5f);
  float4 gv = *(const float4*)(g + t * 4);
  float4 bv = *(const float4*)(b + t * 4);
  bf16x4 o;
  o[0] = (short)f2b((v.x - mean) * rstd * gv.x + bv.x);
  o[1] = (short)f2b((v.y - mean) * rstd * gv.y + bv.y);
  o[2] = (short)f2b((v.z - mean) * rstd * gv.z + bv.z);
  o[3] = (short)f2b((v.w - mean) * rstd * gv.w + bv.w);
  *(bf16x4*)(y + (size_t)row * DMODEL + t * 4) = o;
}

// ---------------------------------------------------------------------------
// GELU (GPT-2 'gelu_new')
// ---------------------------------------------------------------------------
__device__ __forceinline__ float gelu_new_f(float x) {
  const float c = 0.7978845608028654f;  // sqrt(2/pi)
  float u = c * (x + 0.044715f * x * x * x);
  float e = __expf(2.f * u);
  float t = 1.f - 2.f / (e + 1.f);
  return 0.5f * x * (1.f + t);
}

// ---------------------------------------------------------------------------
// Weight convert+transpose: W fp32 [K][N] -> Wt bf16 [N][K]. 64x64 LDS tile.
// ---------------------------------------------------------------------------
__global__ __launch_bounds__(256)
void wconv_kernel(const float* __restrict__ W, short* __restrict__ Wt,
                  int K, int N) {
  const int n0 = blockIdx.x * 64, k0 = blockIdx.y * 64;
  const int t = threadIdx.x;
  __shared__ short tile[64][72];
  #pragma unroll
  for (int i = 0; i < 4; ++i) {
    const int row = i * 16 + (t >> 4);      // k within tile
    const int col4 = (t & 15) * 4;          // n within tile
    float4 v = *(const float4*)(W + (size_t)(k0 + row) * N + n0 + col4);
    tile[col4 + 0][row] = (short)f2b(v.x);
    tile[col4 + 1][row] = (short)f2b(v.y);
    tile[col4 + 2][row] = (short)f2b(v.z);
    tile[col4 + 3][row] = (short)f2b(v.w);
  }
  __syncthreads();
  #pragma unroll
  for (int i = 0; i < 2; ++i) {
    const int cc = t + i * 256;
    const int nr = cc >> 3, k8 = (cc & 7) * 8;
    bf16x8 vv;
    #pragma unroll
    for (int j = 0; j < 8; ++j) vv[j] = tile[nr][k8 + j];
    *(bf16x8*)(Wt + (size_t)(n0 + nr) * K + k0 + k8) = vv;
  }
}

// ---------------------------------------------------------------------------
// bf16 MFMA GEMM: C[M,N] = A[M,K](bf16) @ Bt[N,K](bf16)^T + bias (+R fp32)
// 128x128 tile, BK=64, 4 waves (2x2 of 64x64), mfma_f32_16x16x32_bf16.
// Staging: global_load_lds 16B with PRE-SWIZZLED global source; LDS logical
// [row][64k] with byte^=((row&7)<<4) swizzle; ds_read_b128 applies same XOR.
// ---------------------------------------------------------------------------
template <bool OUTBF, bool GELU, bool RES>
__global__ __launch_bounds__(256)
void gemm_bf16(const short* __restrict__ A, const short* __restrict__ Bt,
               const float* __restrict__ bias, const float* __restrict__ R,
               void* __restrict__ C, int M, int N, int K) {
  __shared__ short As[128 * 64];
  __shared__ short Bs[128 * 64];
  const int t = threadIdx.x, lane = t & 63, w = t >> 6;
  const int g = lane >> 4, la = lane & 15;
  const int bn = blockIdx.x, bm = blockIdx.y;
  const int wm = w >> 1, wn = w & 1;

  // staging coords: thread t stages 16B chunks; linear LDS off = (i*256+t)*16.
  // row = i*32 + (t>>3); global col pre-swizzled so LDS linear == swizzled.
  const int srow = t >> 3;
  const int scolb = ((t & 7) * 16) ^ ((srow & 7) << 4);  // byte offset in row
  const short* Ag = A + (size_t)(bm * 128 + srow) * K + (scolb >> 1);
  const short* Bg = Bt + (size_t)(bn * 128 + srow) * K + (scolb >> 1);
  short* Asl = As + t * 8;
  short* Bsl = Bs + t * 8;

  f32x4 acc[4][4];
  #pragma unroll
  for (int i = 0; i < 4; ++i)
    #pragma unroll
    for (int j = 0; j < 4; ++j) acc[i][j] = (f32x4){0.f, 0.f, 0.f, 0.f};

  const int KT = K >> 6;
  for (int kt = 0; kt < KT; ++kt) {
    __syncthreads();
    #pragma unroll
    for (int i = 0; i < 4; ++i) {
      gl16(Ag + (size_t)i * 32 * K + kt * 64, Asl + i * 2048);
      gl16(Bg + (size_t)i * 32 * K + kt * 64, Bsl + i * 2048);
    }
    __syncthreads();  // compiler emits vmcnt(0) drain before barrier
    #pragma unroll
    for (int ks = 0; ks < 2; ++ks) {
      bf16x8 af[4], bfr[4];
      #pragma unroll
      for (int mi = 0; mi < 4; ++mi) {
        const int row = wm * 64 + mi * 16 + la;
        af[mi] = *(const bf16x8*)((const char*)As + row * 128 +
                                  ((ks * 64 + g * 16) ^ ((row & 7) << 4)));
      }
      #pragma unroll
      for (int ni = 0; ni < 4; ++ni) {
        const int row = wn * 64 + ni * 16 + la;
        bfr[ni] = *(const bf16x8*)((const char*)Bs + row * 128 +
                                   ((ks * 64 + g * 16) ^ ((row & 7) << 4)));
      }
      #pragma unroll
      for (int mi = 0; mi < 4; ++mi)
        #pragma unroll
        for (int ni = 0; ni < 4; ++ni)
          acc[mi][ni] = __builtin_amdgcn_mfma_f32_16x16x32_bf16(
              af[mi], bfr[ni], acc[mi][ni], 0, 0, 0);
    }
  }

  // epilogue: C[row=(g*4+r within frag)][col=la within frag]
  const int crow0 = bm * 128 + wm * 64 + g * 4;
  const int ccol0 = bn * 128 + wn * 64 + la;
  float bl[4];
  #pragma unroll
  for (int ni = 0; ni < 4; ++ni) bl[ni] = bias[ccol0 + ni * 16];
  #pragma unroll
  for (int mi = 0; mi < 4; ++mi) {
    #pragma unroll
    for (int r = 0; r < 4; ++r) {
      const size_t row = (size_t)(crow0 + mi * 16 + r);
      #pragma unroll
      for (int ni = 0; ni < 4; ++ni) {
        float v = acc[mi][ni][r] + bl[ni];
        if (GELU) v = gelu_new_f(v);
        if (RES) v += R[row * N + ccol0 + ni * 16];
        if (OUTBF)
          ((short*)C)[row * N + ccol0 + ni * 16] = (short)f2b(v);
        else
          ((float*)C)[row * N + ccol0 + ni * 16] = v;
      }
    }
  }
}

// ---------------------------------------------------------------------------
// Prep: qkv bf16 [b][s][3*D] -> Qb (x0.125), Kb bf16 [b][h][s][64],
//       Vtb bf16 [b][h][64][s]  (V transposed via LDS tile)
// ---------------------------------------------------------------------------
__global__ __launch_bounds__(256)
void prep_kernel(const short* __restrict__ qkv, short* __restrict__ Qb,
                 short* __restrict__ Kb, short* __restrict__ Vtb) {
  const int st = blockIdx.x, h = blockIdx.y, b = blockIdx.z;
  const int t = threadIdx.x;
  const int s0 = st * 64;
  const size_t bh = (size_t)b * NHEAD + h;
  __shared__ short vt[64][72];
  #pragma unroll
  for (int i = 0; i < 2; ++i) {
    const int cc = t + i * 256;
    const int r = cc >> 3, d8 = (cc & 7) * 8;
    const short* src = qkv + ((size_t)b * SEQ + s0 + r) * 3072 + h * 64 + d8;
    bf16x8 q8 = *(const bf16x8*)(src);
    #pragma unroll
    for (int j = 0; j < 8; ++j) q8[j] = (short)f2b(b2f(q8[j]) * 0.125f);
    *(bf16x8*)(Qb + (bh * SEQ + s0 + r) * 64 + d8) = q8;
    bf16x8 k8 = *(const bf16x8*)(src + 1024);
    *(bf16x8*)(Kb + (bh * SEQ + s0 + r) * 64 + d8) = k8;
    bf16x8 v8 = *(const bf16x8*)(src + 2048);
    #pragma unroll
    for (int j = 0; j < 8; ++j) vt[d8 + j][r] = v8[j];
  }
  __syncthreads();
  #pragma unroll
  for (int i = 0; i < 2; ++i) {
    const int cc = t + i * 256;
    const int d = cc >> 3, s8 = (cc & 7) * 8;
    bf16x8 vv;
    #pragma unroll
    for (int j = 0; j < 8; ++j) vv[j] = vt[d][s8 + j];
    *(bf16x8*)(Vtb + (bh * 64 + d) * SEQ + s0 + s8) = vv;
  }
}

// ---------------------------------------------------------------------------
// bf16 MFMA causal flash attention (validated round 3). bf16 output now.
// ---------------------------------------------------------------------------
__global__ __launch_bounds__(256)
void mha_kernel(const short* __restrict__ Qb, const short* __restrict__ Kb,
                const short* __restrict__ Vtb, short* __restrict__ out) {
  const int qt = blockIdx.x, h = blockIdx.y, b = blockIdx.z;
  const int t = threadIdx.x, lane = t & 63, w = t >> 6;
  const int g = lane >> 4, la = lane & 15;
  const size_t bh = (size_t)b * NHEAD + h;

  __shared__ short Ks[64 * 64];
  __shared__ short Vts[64 * 64];
  __shared__ short Ps[4][16 * 64];

  const short* qrow = Qb + (bh * SEQ + (size_t)qt * 64 + w * 16 + la) * 64;
  const bf16x8 qf0 = *(const bf16x8*)(qrow + g * 8);
  const bf16x8 qf1 = *(const bf16x8*)(qrow + 32 + g * 8);

  float o[16];
  #pragma unroll
  for (int i = 0; i < 16; ++i) o[i] = 0.f;
  float m = -1e30f, l = 0.f;

  const int sr0 = t >> 3, sc8 = (t & 7) * 8;

  for (int kt = 0; kt <= qt; ++kt) {
    const int k0 = kt * 64;
    __syncthreads();
    #pragma unroll
    for (int i = 0; i < 2; ++i) {
      const int r = sr0 + i * 32;
      bf16x8 kv = *(const bf16x8*)(Kb + (bh * SEQ + k0 + r) * 64 + sc8);
      bf16x8 vv = *(const bf16x8*)(Vtb + (bh * 64 + r) * SEQ + k0 + sc8);
      const int lb = r * 128 + ((sc8 * 2) ^ ((r & 7) << 4));
      *(bf16x8*)((char*)Ks + lb) = kv;
      *(bf16x8*)((char*)Vts + lb) = vv;
    }
    __syncthreads();

    float sv[16];
    #pragma unroll
    for (int mt = 0; mt < 4; ++mt) {
      const int ar = mt * 16 + la;
      const int ab = ar * 128 + ((g * 16) ^ ((ar & 7) << 4));
      bf16x8 ka0 = *(const bf16x8*)((char*)Ks + ab);
      bf16x8 ka1 = *(const bf16x8*)((char*)Ks + (ab ^ 64));
      f32x4 sa = {0.f, 0.f, 0.f, 0.f};
      sa = __builtin_amdgcn_mfma_f32_16x16x32_bf16(ka0, qf0, sa, 0, 0, 0);
      sa = __builtin_amdgcn_mfma_f32_16x16x32_bf16(ka1, qf1, sa, 0, 0, 0);
      sv[mt * 4 + 0] = sa[0]; sv[mt * 4 + 1] = sa[1];
      sv[mt * 4 + 2] = sa[2]; sv[mt * 4 + 3] = sa[3];
    }

    if (kt == qt) {  // causal mask on the diagonal tile
      const int qrel = w * 16 + la;
      #pragma unroll
      for (int idx = 0; idx < 16; ++idx) {
        const int krel = (idx >> 2) * 16 + g * 4 + (idx & 3);
        if (krel > qrel) sv[idx] = -10000.0f;
      }
    }

    float tmax = sv[0];
    #pragma unroll
    for (int i = 1; i < 16; ++i) tmax = fmaxf(tmax, sv[i]);
    tmax = fmaxf(tmax, __shfl_xor(tmax, 16));
    tmax = fmaxf(tmax, __shfl_xor(tmax, 32));
    const float mn = fmaxf(m, tmax);
    const float sc = __expf(m - mn);
    m = mn;
    float ps = 0.f;
    #pragma unroll
    for (int i = 0; i < 16; ++i) { sv[i] = __expf(sv[i] - mn); ps += sv[i]; }
    ps += __shfl_xor(ps, 16);
    ps += __shfl_xor(ps, 32);
    l = l * sc + ps;
    #pragma unroll
    for (int r = 0; r < 4; ++r) {
      const float scr = __shfl(sc, (g << 2) + r);
      o[r] *= scr; o[4 + r] *= scr; o[8 + r] *= scr; o[12 + r] *= scr;
    }
    #pragma unroll
    for (int mt = 0; mt < 4; ++mt) {
      #pragma unroll
      for (int r2 = 0; r2 < 2; ++r2) {
        const unsigned pk = (unsigned)f2b(sv[mt * 4 + r2 * 2]) |
                            ((unsigned)f2b(sv[mt * 4 + r2 * 2 + 1]) << 16);
        const int kk = mt * 16 + g * 4 + r2 * 2;
        const int pb = la * 128 + ((kk * 2) ^ ((la & 7) << 4));
        *(unsigned*)((char*)Ps[w] + pb) = pk;
      }
    }
    asm volatile("s_waitcnt lgkmcnt(0)" ::: "memory");
    __builtin_amdgcn_sched_barrier(0);

    const int pb0 = la * 128 + ((g * 16) ^ ((la & 7) << 4));
    const bf16x8 pa0 = *(const bf16x8*)((char*)Ps[w] + pb0);
    const bf16x8 pa1 = *(const bf16x8*)((char*)Ps[w] + (pb0 ^ 64));
    #pragma unroll
    for (int nt = 0; nt < 4; ++nt) {
      const int dr = nt * 16 + la;
      const int vb = dr * 128 + ((g * 16) ^ ((dr & 7) << 4));
      bf16x8 vb0 = *(const bf16x8*)((char*)Vts + vb);
      bf16x8 vb1 = *(const bf16x8*)((char*)Vts + (vb ^ 64));
      f32x4 oa = {o[nt * 4 + 0], o[nt * 4 + 1], o[nt * 4 + 2], o[nt * 4 + 3]};
      oa = __builtin_amdgcn_mfma_f32_16x16x32_bf16(pa0, vb0, oa, 0, 0, 0);
      oa = __builtin_amdgcn_mfma_f32_16x16x32_bf16(pa1, vb1, oa, 0, 0, 0);
      o[nt * 4 + 0] = oa[0]; o[nt * 4 + 1] = oa[1];
      o[nt * 4 + 2] = oa[2]; o[nt * 4 + 3] = oa[3];
    }
  }

  const float linv = 1.f / l;
  #pragma unroll
  for (int r = 0; r < 4; ++r) {
    const float li = __shfl(linv, (g << 2) + r);
    const int qrow_g = qt * 64 + w * 16 + g * 4 + r;
    #pragma unroll
    for (int nt = 0; nt < 4; ++nt) {
      out[((size_t)b * SEQ + qrow_g) * DMODEL + h * 64 + nt * 16 + la] =
          (short)f2b(o[nt * 4 + r] * li);
    }
  }
}

// ---------------------------------------------------------------------------
// Launcher
// ---------------------------------------------------------------------------
extern "C" void kernel_launch(void* const* d_in, const int* in_sizes, int n_in,
                              void* d_out, int out_size, void* d_ws, size_t ws_size,
                              hipStream_t stream) {
  const float* hidden      = (const float*)d_in[0];
  const float* ln1_g       = (const float*)d_in[1];
  const float* ln1_b       = (const float*)d_in[2];
  const float* w_attn      = (const float*)d_in[3];
  const float* b_attn      = (const float*)d_in[4];
  const float* w_attn_proj = (const float*)d_in[5];
  const float* b_attn_proj = (const float*)d_in[6];
  const float* ln2_g       = (const float*)d_in[7];
  const float* ln2_b       = (const float*)d_in[8];
  const float* w_fc        = (const float*)d_in[9];
  const float* b_fc        = (const float*)d_in[10];
  const float* w_mlp_proj  = (const float*)d_in[11];
  const float* b_mlp_proj  = (const float*)d_in[12];
  float* out = (float*)d_out;

  const int Bn = in_sizes[0] / (SEQ * DMODEL);  // batch (=4)
  const int M = Bn * SEQ;                        // 8192 rows

  // Workspace layout (bytes, total ~210MB <= 235MB budget):
  char* W = (char*)d_ws;
  const size_t szMD2 = (size_t)M * DMODEL * 2;        // 16.8MB
  short* xln_b  = (short*)W;                          // LN out (reused LN1/LN2)
  short* qkv_b  = (short*)(W + szMD2);                // qkv bf16, later a1 bf16
  short* a1_b   = qkv_b;                              // [M,FF] bf16 (67.1MB region)
  char*  p2     = W + szMD2 + (size_t)M * FFDIM * 2;
  short* Qb     = (short*)p2;                         // 3x 16.8MB
  short* Kb     = Qb + (size_t)M * DMODEL;
  short* Vtb    = Kb + (size_t)M * DMODEL;
  short* attn_b = Vtb + (size_t)M * DMODEL;           // 16.8MB
  float* h2     = (float*)(p2 + 4 * szMD2);           // fp32 33.6MB
  short* wat    = (short*)(p2 + 4 * szMD2 + (size_t)M * DMODEL * 4);
  short* wpt    = wat + (size_t)3 * DMODEL * DMODEL;  // [1024,1024]
  short* wft    = wpt + (size_t)DMODEL * DMODEL;      // [4096,1024]
  short* wmt    = wft + (size_t)FFDIM * DMODEL;       // [1024,4096]

  // 0. weight convert+transpose (per-call; no static state allowed)
  wconv_kernel<<<dim3(3 * DMODEL / 64, DMODEL / 64), 256, 0, stream>>>(
      w_attn, wat, DMODEL, 3 * DMODEL);
  wconv_kernel<<<dim3(DMODEL / 64, DMODEL / 64), 256, 0, stream>>>(
      w_attn_proj, wpt, DMODEL, DMODEL);
  wconv_kernel<<<dim3(FFDIM / 64, DMODEL / 64), 256, 0, stream>>>(
      w_fc, wft, DMODEL, FFDIM);
  wconv_kernel<<<dim3(DMODEL / 64, FFDIM / 64), 256, 0, stream>>>(
      w_mlp_proj, wmt, FFDIM, DMODEL);

  // 1. LN1 -> bf16
  ln_kernel<<<M, 256, 0, stream>>>(hidden, ln1_g, ln1_b, xln_b);
  // 2. QKV = xln @ w_attn + b  -> bf16 [M,3072]
  gemm_bf16<true, false, false><<<dim3(3 * DMODEL / 128, M / 128), 256, 0, stream>>>(
      xln_b, wat, b_attn, nullptr, qkv_b, M, 3 * DMODEL, DMODEL);
  // 2.5 split/scale/transpose QKV
  prep_kernel<<<dim3(SEQ / 64, NHEAD, Bn), 256, 0, stream>>>(qkv_b, Qb, Kb, Vtb);
  // 3. attention -> bf16 [M,1024]
  mha_kernel<<<dim3(SEQ / 64, NHEAD, Bn), 256, 0, stream>>>(Qb, Kb, Vtb, attn_b);
  // 4. h2 = hidden + attn @ w_attn_proj + b   (fp32)
  gemm_bf16<false, false, true><<<dim3(DMODEL / 128, M / 128), 256, 0, stream>>>(
      attn_b, wpt, b_attn_proj, hidden, h2, M, DMODEL, DMODEL);
  // 5. LN2 -> bf16
  ln_kernel<<<M, 256, 0, stream>>>(h2, ln2_g, ln2_b, xln_b);
  // 6. a1 = gelu(xln2 @ w_fc + b) -> bf16 [M,4096]  (overwrites dead qkv_b)
  gemm_bf16<true, true, false><<<dim3(FFDIM / 128, M / 128), 256, 0, stream>>>(
      xln_b, wft, b_fc, nullptr, a1_b, M, FFDIM, DMODEL);
  // 7. out = h2 + a1 @ w_mlp_proj + b  (fp32)
  gemm_bf16<false, false, true><<<dim3(DMODEL / 128, M / 128), 256, 0, stream>>>(
      a1_b, wmt, b_mlp_proj, h2, out, M, DMODEL, FFDIM);
}

// Round 6
// 565.294 us; speedup vs baseline: 15.7192x; 1.0943x over previous
//
#include <hip/hip_runtime.h>
#include <hip/hip_bf16.h>
#include <cstddef>

// GPT-2 block. B=4 (derived), S=2048, D=1024, H=16, DH=64, FF=4096.
#define SEQ   2048
#define DMODEL 1024
#define NHEAD 16
#define HDIM  64
#define FFDIM 4096
#define QT    (SEQ / 64)   // 32 q-tiles

typedef __attribute__((ext_vector_type(8))) short bf16x8;
typedef __attribute__((ext_vector_type(4))) short bf16x4;
typedef __attribute__((ext_vector_type(4))) float f32x4;

__device__ __forceinline__ unsigned short f2b(float x) {
  __hip_bfloat16 h = __float2bfloat16(x);
  return __builtin_bit_cast(unsigned short, h);
}
__device__ __forceinline__ float b2f(short u) {
  unsigned x = ((unsigned)(unsigned short)u) << 16;
  return __builtin_bit_cast(float, x);
}
// async global->LDS, 16B per lane. LDS dest = wave-uniform base + lane*16.
__device__ __forceinline__ void gl16(const short* g, short* l) {
  __builtin_amdgcn_global_load_lds(
      (const __attribute__((address_space(1))) void*)g,
      (__attribute__((address_space(3))) void*)l, 16, 0, 0);
}

// ---------------------------------------------------------------------------
// LayerNorm: one block per row, 256 threads, float4/thread; bf16 output.
// ---------------------------------------------------------------------------
__global__ __launch_bounds__(256)
void ln_kernel(const float* __restrict__ x, const float* __restrict__ g,
               const float* __restrict__ b, short* __restrict__ y) {
  const int row = blockIdx.x;
  const int t = threadIdx.x;
  const float* xr = x + (size_t)row * DMODEL;
  float4 v = *(const float4*)(xr + t * 4);
  float s = v.x + v.y + v.z + v.w;
  float q = v.x * v.x + v.y * v.y + v.z * v.z + v.w * v.w;
  #pragma unroll
  for (int off = 32; off; off >>= 1) {
    s += __shfl_xor(s, off);
    q += __shfl_xor(q, off);
  }
  __shared__ float ss[4], qq[4];
  if ((t & 63) == 0) { ss[t >> 6] = s; qq[t >> 6] = q; }
  __syncthreads();
  s = ss[0] + ss[1] + ss[2] + ss[3];
  q = qq[0] + qq[1] + qq[2] + qq[3];
  const float mean = s * (1.f / DMODEL);
  const float var = q * (1.f / DMODEL) - mean * mean;
  const float rstd = rsqrtf(var + 1e-5f);
  float4 gv = *(const float4*)(g + t * 4);
  float4 bv = *(const float4*)(b + t * 4);
  bf16x4 o;
  o[0] = (short)f2b((v.x - mean) * rstd * gv.x + bv.x);
  o[1] = (short)f2b((v.y - mean) * rstd * gv.y + bv.y);
  o[2] = (short)f2b((v.z - mean) * rstd * gv.z + bv.z);
  o[3] = (short)f2b((v.w - mean) * rstd * gv.w + bv.w);
  *(bf16x4*)(y + (size_t)row * DMODEL + t * 4) = o;
}

// ---------------------------------------------------------------------------
// GELU (GPT-2 'gelu_new')
// ---------------------------------------------------------------------------
__device__ __forceinline__ float gelu_new_f(float x) {
  const float c = 0.7978845608028654f;  // sqrt(2/pi)
  float u = c * (x + 0.044715f * x * x * x);
  float e = __expf(2.f * u);
  float t = 1.f - 2.f / (e + 1.f);
  return 0.5f * x * (1.f + t);
}

// ---------------------------------------------------------------------------
// Fused weight convert+transpose for all 4 weights: fp32 [K][N] -> bf16 [N][K]
// ---------------------------------------------------------------------------
__global__ __launch_bounds__(256)
void wconv4_kernel(const float* __restrict__ w0, short* __restrict__ t0,
                   const float* __restrict__ w1, short* __restrict__ t1,
                   const float* __restrict__ w2, short* __restrict__ t2,
                   const float* __restrict__ w3, short* __restrict__ t3) {
  int id = blockIdx.x;
  const float* W; short* Wt; int K, N;
  if (id < 768)       { W = w0; Wt = t0; K = 1024; N = 3072; }
  else if (id < 1024) { id -= 768;  W = w1; Wt = t1; K = 1024; N = 1024; }
  else if (id < 2048) { id -= 1024; W = w2; Wt = t2; K = 1024; N = 4096; }
  else                { id -= 2048; W = w3; Wt = t3; K = 4096; N = 1024; }
  const int nt = N >> 6;
  const int n0 = (id % nt) * 64, k0 = (id / nt) * 64;
  const int t = threadIdx.x;
  __shared__ short tile[64][72];
  #pragma unroll
  for (int i = 0; i < 4; ++i) {
    const int row = i * 16 + (t >> 4);      // k within tile
    const int col4 = (t & 15) * 4;          // n within tile
    float4 v = *(const float4*)(W + (size_t)(k0 + row) * N + n0 + col4);
    tile[col4 + 0][row] = (short)f2b(v.x);
    tile[col4 + 1][row] = (short)f2b(v.y);
    tile[col4 + 2][row] = (short)f2b(v.z);
    tile[col4 + 3][row] = (short)f2b(v.w);
  }
  __syncthreads();
  #pragma unroll
  for (int i = 0; i < 2; ++i) {
    const int cc = t + i * 256;
    const int nr = cc >> 3, k8 = (cc & 7) * 8;
    bf16x8 vv;
    #pragma unroll
    for (int j = 0; j < 8; ++j) vv[j] = tile[nr][k8 + j];
    *(bf16x8*)(Wt + (size_t)(n0 + nr) * K + k0 + k8) = vv;
  }
}

// ---------------------------------------------------------------------------
// bf16 MFMA GEMM: C[M,N] = A[M,K](bf16) @ Bt[N,K](bf16)^T + bias (+R fp32)
// 128x128 tile, BK=64, 4 waves, mfma_f32_16x16x32_bf16 (validated round 4).
// ---------------------------------------------------------------------------
template <bool OUTBF, bool GELU, bool RES>
__global__ __launch_bounds__(256)
void gemm_bf16(const short* __restrict__ A, const short* __restrict__ Bt,
               const float* __restrict__ bias, const float* __restrict__ R,
               void* __restrict__ C, int M, int N, int K) {
  __shared__ short As[128 * 64];
  __shared__ short Bs[128 * 64];
  const int t = threadIdx.x, lane = t & 63, w = t >> 6;
  const int g = lane >> 4, la = lane & 15;
  const int bn = blockIdx.x, bm = blockIdx.y;
  const int wm = w >> 1, wn = w & 1;

  const int srow = t >> 3;
  const int scolb = ((t & 7) * 16) ^ ((srow & 7) << 4);  // pre-swizzled byte col
  const short* Ag = A + (size_t)(bm * 128 + srow) * K + (scolb >> 1);
  const short* Bg = Bt + (size_t)(bn * 128 + srow) * K + (scolb >> 1);
  short* Asl = As + t * 8;
  short* Bsl = Bs + t * 8;

  f32x4 acc[4][4];
  #pragma unroll
  for (int i = 0; i < 4; ++i)
    #pragma unroll
    for (int j = 0; j < 4; ++j) acc[i][j] = (f32x4){0.f, 0.f, 0.f, 0.f};

  const int KT = K >> 6;
  for (int kt = 0; kt < KT; ++kt) {
    __syncthreads();
    #pragma unroll
    for (int i = 0; i < 4; ++i) {
      gl16(Ag + (size_t)i * 32 * K + kt * 64, Asl + i * 2048);
      gl16(Bg + (size_t)i * 32 * K + kt * 64, Bsl + i * 2048);
    }
    __syncthreads();
    #pragma unroll
    for (int ks = 0; ks < 2; ++ks) {
      bf16x8 af[4], bfr[4];
      #pragma unroll
      for (int mi = 0; mi < 4; ++mi) {
        const int row = wm * 64 + mi * 16 + la;
        af[mi] = *(const bf16x8*)((const char*)As + row * 128 +
                                  ((ks * 64 + g * 16) ^ ((row & 7) << 4)));
      }
      #pragma unroll
      for (int ni = 0; ni < 4; ++ni) {
        const int row = wn * 64 + ni * 16 + la;
        bfr[ni] = *(const bf16x8*)((const char*)Bs + row * 128 +
                                   ((ks * 64 + g * 16) ^ ((row & 7) << 4)));
      }
      #pragma unroll
      for (int mi = 0; mi < 4; ++mi)
        #pragma unroll
        for (int ni = 0; ni < 4; ++ni)
          acc[mi][ni] = __builtin_amdgcn_mfma_f32_16x16x32_bf16(
              af[mi], bfr[ni], acc[mi][ni], 0, 0, 0);
    }
  }

  const int crow0 = bm * 128 + wm * 64 + g * 4;
  const int ccol0 = bn * 128 + wn * 64 + la;
  float bl[4];
  #pragma unroll
  for (int ni = 0; ni < 4; ++ni) bl[ni] = bias[ccol0 + ni * 16];
  #pragma unroll
  for (int mi = 0; mi < 4; ++mi) {
    #pragma unroll
    for (int r = 0; r < 4; ++r) {
      const size_t row = (size_t)(crow0 + mi * 16 + r);
      #pragma unroll
      for (int ni = 0; ni < 4; ++ni) {
        float v = acc[mi][ni][r] + bl[ni];
        if (GELU) v = gelu_new_f(v);
        if (RES) v += R[row * N + ccol0 + ni * 16];
        if (OUTBF)
          ((short*)C)[row * N + ccol0 + ni * 16] = (short)f2b(v);
        else
          ((float*)C)[row * N + ccol0 + ni * 16] = v;
      }
    }
  }
}

// ---------------------------------------------------------------------------
// Prep: qkv bf16 [b][s][3*D] -> Qb (x 0.125*log2e), Kb bf16 [b][h][s][64],
//       Vtb bf16 [b][h][64][s]  (V transposed via LDS tile)
// ---------------------------------------------------------------------------
__global__ __launch_bounds__(256)
void prep_kernel(const short* __restrict__ qkv, short* __restrict__ Qb,
                 short* __restrict__ Kb, short* __restrict__ Vtb) {
  const int st = blockIdx.x, h = blockIdx.y, b = blockIdx.z;
  const int t = threadIdx.x;
  const int s0 = st * 64;
  const size_t bh = (size_t)b * NHEAD + h;
  const float qscale = 0.125f * 1.44269504088896f;  // fold log2e: exp2 domain
  __shared__ short vt[64][72];
  #pragma unroll
  for (int i = 0; i < 2; ++i) {
    const int cc = t + i * 256;
    const int r = cc >> 3, d8 = (cc & 7) * 8;
    const short* src = qkv + ((size_t)b * SEQ + s0 + r) * 3072 + h * 64 + d8;
    bf16x8 q8 = *(const bf16x8*)(src);
    #pragma unroll
    for (int j = 0; j < 8; ++j) q8[j] = (short)f2b(b2f(q8[j]) * qscale);
    *(bf16x8*)(Qb + (bh * SEQ + s0 + r) * 64 + d8) = q8;
    bf16x8 k8 = *(const bf16x8*)(src + 1024);
    *(bf16x8*)(Kb + (bh * SEQ + s0 + r) * 64 + d8) = k8;
    bf16x8 v8 = *(const bf16x8*)(src + 2048);
    #pragma unroll
    for (int j = 0; j < 8; ++j) vt[d8 + j][r] = v8[j];
  }
  __syncthreads();
  #pragma unroll
  for (int i = 0; i < 2; ++i) {
    const int cc = t + i * 256;
    const int d = cc >> 3, s8 = (cc & 7) * 8;
    bf16x8 vv;
    #pragma unroll
    for (int j = 0; j < 8; ++j) vv[j] = vt[d][s8 + j];
    *(bf16x8*)(Vtb + (bh * 64 + d) * SEQ + s0 + s8) = vv;
  }
}

// ---------------------------------------------------------------------------
// bf16 MFMA causal flash attention, log2-domain softmax.
// Block = paired q-tiles (p, QT-1-p) -> exactly QT+1 K-tile iterations each:
// perfect load balance (was 1..32 triangular). 4 waves x 16 q-rows.
// K/Vt staged via global_load_lds with pre-swizzled source (rule #21).
// Defer-max (T13): skip O-rescale when tile max <= m + 11.5 (log2 domain).
// ---------------------------------------------------------------------------
__global__ __launch_bounds__(256)
void mha_kernel(const short* __restrict__ Qb, const short* __restrict__ Kb,
                const short* __restrict__ Vtb, short* __restrict__ out) {
  const int p = blockIdx.x, h = blockIdx.y, b = blockIdx.z;
  const int t = threadIdx.x, lane = t & 63, w = t >> 6;
  const int g = lane >> 4, la = lane & 15;
  const size_t bh = (size_t)b * NHEAD + h;

  __shared__ short Ks[64 * 64];
  __shared__ short Vts[64 * 64];
  __shared__ short Ps[4][16 * 64];

  const int srow = t >> 3;
  const int scolb = ((t & 7) * 16) ^ ((srow & 7) << 4);  // pre-swizzled

  #pragma unroll 1
  for (int e = 0; e < 2; ++e) {
    const int qt = e ? (QT - 1 - p) : p;

    const short* qrow = Qb + (bh * SEQ + (size_t)qt * 64 + w * 16 + la) * 64;
    const bf16x8 qf0 = *(const bf16x8*)(qrow + g * 8);
    const bf16x8 qf1 = *(const bf16x8*)(qrow + 32 + g * 8);

    float o[16];
    #pragma unroll
    for (int i = 0; i < 16; ++i) o[i] = 0.f;
    float m = -1e30f, l = 0.f;

    for (int kt = 0; kt <= qt; ++kt) {
      const int k0 = kt * 64;
      __syncthreads();
      #pragma unroll
      for (int i = 0; i < 2; ++i) {
        const int r = srow + i * 32;
        gl16(Kb + (bh * SEQ + k0 + r) * 64 + (scolb >> 1), Ks + i * 2048 + t * 8);
        gl16(Vtb + (bh * 64 + r) * SEQ + k0 + (scolb >> 1), Vts + i * 2048 + t * 8);
      }
      __syncthreads();  // implicit vmcnt(0) drain

      float sv[16];
      #pragma unroll
      for (int mt = 0; mt < 4; ++mt) {
        const int ar = mt * 16 + la;
        const int ab = ar * 128 + ((g * 16) ^ ((ar & 7) << 4));
        bf16x8 ka0 = *(const bf16x8*)((char*)Ks + ab);
        bf16x8 ka1 = *(const bf16x8*)((char*)Ks + (ab ^ 64));
        f32x4 sa = {0.f, 0.f, 0.f, 0.f};
        sa = __builtin_amdgcn_mfma_f32_16x16x32_bf16(ka0, qf0, sa, 0, 0, 0);
        sa = __builtin_amdgcn_mfma_f32_16x16x32_bf16(ka1, qf1, sa, 0, 0, 0);
        sv[mt * 4 + 0] = sa[0]; sv[mt * 4 + 1] = sa[1];
        sv[mt * 4 + 2] = sa[2]; sv[mt * 4 + 3] = sa[3];
      }

      if (kt == qt) {  // causal mask (log2 domain: -10000*log2e)
        const int qrel = w * 16 + la;
        #pragma unroll
        for (int idx = 0; idx < 16; ++idx) {
          const int krel = (idx >> 2) * 16 + g * 4 + (idx & 3);
          if (krel > qrel) sv[idx] = -14426.950408889634f;
        }
      }

      // tree max over 16, then cross-g (lanes share la -> per-q-row max)
      float t8[8], t4[4], t2[2];
      #pragma unroll
      for (int i = 0; i < 8; ++i) t8[i] = fmaxf(sv[2 * i], sv[2 * i + 1]);
      #pragma unroll
      for (int i = 0; i < 4; ++i) t4[i] = fmaxf(t8[2 * i], t8[2 * i + 1]);
      t2[0] = fmaxf(t4[0], t4[1]); t2[1] = fmaxf(t4[2], t4[3]);
      float tmax = fmaxf(t2[0], t2[1]);
      tmax = fmaxf(tmax, __shfl_xor(tmax, 16));
      tmax = fmaxf(tmax, __shfl_xor(tmax, 32));

      const bool skip = __all(tmax <= m + 11.5f) != 0;  // e^8 in log2 domain
      const float mn = skip ? m : fmaxf(m, tmax);

      float ss8[8], ss4[4];
      #pragma unroll
      for (int i = 0; i < 16; ++i) sv[i] = exp2f(sv[i] - mn);
      #pragma unroll
      for (int i = 0; i < 8; ++i) ss8[i] = sv[2 * i] + sv[2 * i + 1];
      #pragma unroll
      for (int i = 0; i < 4; ++i) ss4[i] = ss8[2 * i] + ss8[2 * i + 1];
      float ps = (ss4[0] + ss4[1]) + (ss4[2] + ss4[3]);
      ps += __shfl_xor(ps, 16);
      ps += __shfl_xor(ps, 32);

      if (skip) {
        l += ps;
      } else {
        const float sc = exp2f(m - mn);
        l = l * sc + ps;
        m = mn;
        #pragma unroll
        for (int r = 0; r < 4; ++r) {
          const float scr = __shfl(sc, (g << 2) + r);
          o[r] *= scr; o[4 + r] *= scr; o[8 + r] *= scr; o[12 + r] *= scr;
        }
      }

      // write P (bf16) to per-wave swizzled LDS
      #pragma unroll
      for (int mt = 0; mt < 4; ++mt) {
        #pragma unroll
        for (int r2 = 0; r2 < 2; ++r2) {
          const unsigned pk = (unsigned)f2b(sv[mt * 4 + r2 * 2]) |
                              ((unsigned)f2b(sv[mt * 4 + r2 * 2 + 1]) << 16);
          const int kk = mt * 16 + g * 4 + r2 * 2;
          const int pb = la * 128 + ((kk * 2) ^ ((la & 7) << 4));
          *(unsigned*)((char*)Ps[w] + pb) = pk;
        }
      }
      // same-wave cross-lane LDS RAW hazard: drain + pin (rule #18)
      asm volatile("s_waitcnt lgkmcnt(0)" ::: "memory");
      __builtin_amdgcn_sched_barrier(0);

      const int pb0 = la * 128 + ((g * 16) ^ ((la & 7) << 4));
      const bf16x8 pa0 = *(const bf16x8*)((char*)Ps[w] + pb0);
      const bf16x8 pa1 = *(const bf16x8*)((char*)Ps[w] + (pb0 ^ 64));
      #pragma unroll
      for (int nt = 0; nt < 4; ++nt) {
        const int dr = nt * 16 + la;
        const int vb = dr * 128 + ((g * 16) ^ ((dr & 7) << 4));
        bf16x8 vb0 = *(const bf16x8*)((char*)Vts + vb);
        bf16x8 vb1 = *(const bf16x8*)((char*)Vts + (vb ^ 64));
        f32x4 oa = {o[nt * 4 + 0], o[nt * 4 + 1], o[nt * 4 + 2], o[nt * 4 + 3]};
        oa = __builtin_amdgcn_mfma_f32_16x16x32_bf16(pa0, vb0, oa, 0, 0, 0);
        oa = __builtin_amdgcn_mfma_f32_16x16x32_bf16(pa1, vb1, oa, 0, 0, 0);
        o[nt * 4 + 0] = oa[0]; o[nt * 4 + 1] = oa[1];
        o[nt * 4 + 2] = oa[2]; o[nt * 4 + 3] = oa[3];
      }
    }

    const float linv = 1.f / l;
    #pragma unroll
    for (int r = 0; r < 4; ++r) {
      const float li = __shfl(linv, (g << 2) + r);
      const int qrow_g = qt * 64 + w * 16 + g * 4 + r;
      #pragma unroll
      for (int nt = 0; nt < 4; ++nt) {
        out[((size_t)b * SEQ + qrow_g) * DMODEL + h * 64 + nt * 16 + la] =
            (short)f2b(o[nt * 4 + r] * li);
      }
    }
  }
}

// ---------------------------------------------------------------------------
// Launcher
// ---------------------------------------------------------------------------
extern "C" void kernel_launch(void* const* d_in, const int* in_sizes, int n_in,
                              void* d_out, int out_size, void* d_ws, size_t ws_size,
                              hipStream_t stream) {
  const float* hidden      = (const float*)d_in[0];
  const float* ln1_g       = (const float*)d_in[1];
  const float* ln1_b       = (const float*)d_in[2];
  const float* w_attn      = (const float*)d_in[3];
  const float* b_attn      = (const float*)d_in[4];
  const float* w_attn_proj = (const float*)d_in[5];
  const float* b_attn_proj = (const float*)d_in[6];
  const float* ln2_g       = (const float*)d_in[7];
  const float* ln2_b       = (const float*)d_in[8];
  const float* w_fc        = (const float*)d_in[9];
  const float* b_fc        = (const float*)d_in[10];
  const float* w_mlp_proj  = (const float*)d_in[11];
  const float* b_mlp_proj  = (const float*)d_in[12];
  float* out = (float*)d_out;

  const int Bn = in_sizes[0] / (SEQ * DMODEL);  // batch (=4)
  const int M = Bn * SEQ;                        // 8192 rows

  // Workspace layout (bytes, ~210MB):
  char* W = (char*)d_ws;
  const size_t szMD2 = (size_t)M * DMODEL * 2;        // 16.8MB
  short* xln_b  = (short*)W;
  short* qkv_b  = (short*)(W + szMD2);                // qkv bf16 / a1 bf16
  short* a1_b   = qkv_b;
  char*  p2     = W + szMD2 + (size_t)M * FFDIM * 2;
  short* Qb     = (short*)p2;
  short* Kb     = Qb + (size_t)M * DMODEL;
  short* Vtb    = Kb + (size_t)M * DMODEL;
  short* attn_b = Vtb + (size_t)M * DMODEL;
  float* h2     = (float*)(p2 + 4 * szMD2);
  short* wat    = (short*)(p2 + 4 * szMD2 + (size_t)M * DMODEL * 4);
  short* wpt    = wat + (size_t)3 * DMODEL * DMODEL;
  short* wft    = wpt + (size_t)DMODEL * DMODEL;
  short* wmt    = wft + (size_t)FFDIM * DMODEL;

  // 0. fused weight convert+transpose (768+256+1024+1024 = 3072 tiles)
  wconv4_kernel<<<3072, 256, 0, stream>>>(w_attn, wat, w_attn_proj, wpt,
                                          w_fc, wft, w_mlp_proj, wmt);
  // 1. LN1 -> bf16
  ln_kernel<<<M, 256, 0, stream>>>(hidden, ln1_g, ln1_b, xln_b);
  // 2. QKV = xln @ w_attn + b  -> bf16 [M,3072]
  gemm_bf16<true, false, false><<<dim3(3 * DMODEL / 128, M / 128), 256, 0, stream>>>(
      xln_b, wat, b_attn, nullptr, qkv_b, M, 3 * DMODEL, DMODEL);
  // 2.5 split/scale/transpose QKV
  prep_kernel<<<dim3(SEQ / 64, NHEAD, Bn), 256, 0, stream>>>(qkv_b, Qb, Kb, Vtb);
  // 3. attention -> bf16 [M,1024]  (paired q-tiles: grid.x = QT/2)
  mha_kernel<<<dim3(QT / 2, NHEAD, Bn), 256, 0, stream>>>(Qb, Kb, Vtb, attn_b);
  // 4. h2 = hidden + attn @ w_attn_proj + b   (fp32)
  gemm_bf16<false, false, true><<<dim3(DMODEL / 128, M / 128), 256, 0, stream>>>(
      attn_b, wpt, b_attn_proj, hidden, h2, M, DMODEL, DMODEL);
  // 5. LN2 -> bf16
  ln_kernel<<<M, 256, 0, stream>>>(h2, ln2_g, ln2_b, xln_b);
  // 6. a1 = gelu(xln2 @ w_fc + b) -> bf16 [M,4096]
  gemm_bf16<true, true, false><<<dim3(FFDIM / 128, M / 128), 256, 0, stream>>>(
      xln_b, wft, b_fc, nullptr, a1_b, M, FFDIM, DMODEL);
  // 7. out = h2 + a1 @ w_mlp_proj + b  (fp32)
  gemm_bf16<false, false, true><<<dim3(DMODEL / 128, M / 128), 256, 0, stream>>>(
      a1_b, wmt, b_mlp_proj, h2, out, M, DMODEL, FFDIM);
}

// Round 7
// 552.921 us; speedup vs baseline: 16.0709x; 1.0224x over previous
//
#include <hip/hip_runtime.h>
#include <hip/hip_bf16.h>
#include <cstddef>

// GPT-2 block. B=4 (derived), S=2048, D=1024, H=16, DH=64, FF=4096.
#define SEQ   2048
#define DMODEL 1024
#define NHEAD 16
#define HDIM  64
#define FFDIM 4096
#define QT    (SEQ / 64)   // 32 q-tiles

typedef __attribute__((ext_vector_type(8))) short bf16x8;
typedef __attribute__((ext_vector_type(4))) short bf16x4;
typedef __attribute__((ext_vector_type(4))) float f32x4;

#define QSCALE (0.125f * 1.44269504088896f)  // 1/sqrt(64) * log2(e)

__device__ __forceinline__ unsigned short f2b(float x) {
  __hip_bfloat16 h = __float2bfloat16(x);
  return __builtin_bit_cast(unsigned short, h);
}
__device__ __forceinline__ float b2f(short u) {
  unsigned x = ((unsigned)(unsigned short)u) << 16;
  return __builtin_bit_cast(float, x);
}
// async global->LDS, 16B per lane. LDS dest = wave-uniform base + lane*16.
__device__ __forceinline__ void gl16(const short* g, short* l) {
  __builtin_amdgcn_global_load_lds(
      (const __attribute__((address_space(1))) void*)g,
      (__attribute__((address_space(3))) void*)l, 16, 0, 0);
}

// ---------------------------------------------------------------------------
// LayerNorm: one block per row, 256 threads, float4/thread; bf16 output.
// ---------------------------------------------------------------------------
__global__ __launch_bounds__(256)
void ln_kernel(const float* __restrict__ x, const float* __restrict__ g,
               const float* __restrict__ b, short* __restrict__ y) {
  const int row = blockIdx.x;
  const int t = threadIdx.x;
  const float* xr = x + (size_t)row * DMODEL;
  float4 v = *(const float4*)(xr + t * 4);
  float s = v.x + v.y + v.z + v.w;
  float q = v.x * v.x + v.y * v.y + v.z * v.z + v.w * v.w;
  #pragma unroll
  for (int off = 32; off; off >>= 1) {
    s += __shfl_xor(s, off);
    q += __shfl_xor(q, off);
  }
  __shared__ float ss[4], qq[4];
  if ((t & 63) == 0) { ss[t >> 6] = s; qq[t >> 6] = q; }
  __syncthreads();
  s = ss[0] + ss[1] + ss[2] + ss[3];
  q = qq[0] + qq[1] + qq[2] + qq[3];
  const float mean = s * (1.f / DMODEL);
  const float var = q * (1.f / DMODEL) - mean * mean;
  const float rstd = rsqrtf(var + 1e-5f);
  float4 gv = *(const float4*)(g + t * 4);
  float4 bv = *(const float4*)(b + t * 4);
  bf16x4 o;
  o[0] = (short)f2b((v.x - mean) * rstd * gv.x + bv.x);
  o[1] = (short)f2b((v.y - mean) * rstd * gv.y + bv.y);
  o[2] = (short)f2b((v.z - mean) * rstd * gv.z + bv.z);
  o[3] = (short)f2b((v.w - mean) * rstd * gv.w + bv.w);
  *(bf16x4*)(y + (size_t)row * DMODEL + t * 4) = o;
}

// ---------------------------------------------------------------------------
// GELU (GPT-2 'gelu_new')
// ---------------------------------------------------------------------------
__device__ __forceinline__ float gelu_new_f(float x) {
  const float c = 0.7978845608028654f;  // sqrt(2/pi)
  float u = c * (x + 0.044715f * x * x * x);
  float e = __expf(2.f * u);
  float t = 1.f - 2.f / (e + 1.f);
  return 0.5f * x * (1.f + t);
}

// ---------------------------------------------------------------------------
// Fused weight convert+transpose (fp32 [K][N] -> bf16 [N][K]) for 4 weights.
// Q-columns (n<1024) of w_attn pre-scaled by QSCALE (linearity: folds the
// softmax scale+log2e into the QKV GEMM). Block 3072 scales b_attn likewise.
// ---------------------------------------------------------------------------
__global__ __launch_bounds__(256)
void wconv4_kernel(const float* __restrict__ w0, short* __restrict__ t0,
                   const float* __restrict__ w1, short* __restrict__ t1,
                   const float* __restrict__ w2, short* __restrict__ t2,
                   const float* __restrict__ w3, short* __restrict__ t3,
                   const float* __restrict__ ba, float* __restrict__ bas) {
  int id = blockIdx.x;
  const int t = threadIdx.x;
  if (id == 3072) {  // bias pre-scale for the QKV GEMM
    #pragma unroll
    for (int i = t; i < 3072; i += 256)
      bas[i] = ba[i] * (i < 1024 ? QSCALE : 1.f);
    return;
  }
  const float* W; short* Wt; int K, N;
  float sc = 1.f;
  if (id < 768)       { W = w0; Wt = t0; K = 1024; N = 3072; }
  else if (id < 1024) { id -= 768;  W = w1; Wt = t1; K = 1024; N = 1024; }
  else if (id < 2048) { id -= 1024; W = w2; Wt = t2; K = 1024; N = 4096; }
  else                { id -= 2048; W = w3; Wt = t3; K = 4096; N = 1024; }
  const int nt = N >> 6;
  const int n0 = (id % nt) * 64, k0 = (id / nt) * 64;
  if (W == w0 && n0 < 1024) sc = QSCALE;  // Q column block
  __shared__ short tile[64][72];
  #pragma unroll
  for (int i = 0; i < 4; ++i) {
    const int row = i * 16 + (t >> 4);      // k within tile
    const int col4 = (t & 15) * 4;          // n within tile
    float4 v = *(const float4*)(W + (size_t)(k0 + row) * N + n0 + col4);
    tile[col4 + 0][row] = (short)f2b(v.x * sc);
    tile[col4 + 1][row] = (short)f2b(v.y * sc);
    tile[col4 + 2][row] = (short)f2b(v.z * sc);
    tile[col4 + 3][row] = (short)f2b(v.w * sc);
  }
  __syncthreads();
  #pragma unroll
  for (int i = 0; i < 2; ++i) {
    const int cc = t + i * 256;
    const int nr = cc >> 3, k8 = (cc & 7) * 8;
    bf16x8 vv;
    #pragma unroll
    for (int j = 0; j < 8; ++j) vv[j] = tile[nr][k8 + j];
    *(bf16x8*)(Wt + (size_t)(n0 + nr) * K + k0 + k8) = vv;
  }
}

// ---------------------------------------------------------------------------
// bf16 MFMA GEMM: C[M,N] = A[M,K](bf16) @ Bt[N,K](bf16)^T + bias (+R fp32)
// 128x128 tile, BK=64, 4 waves, mfma_f32_16x16x32_bf16 (validated r4/r6).
// QKVS variant: N=3072; epilogue scatters Q/K/V directly into per-head
// [b][h][s][64] layouts (C=Qb, C2=Kb, C3=Vb). Region is uniform per
// 16-lane fragment (1024-boundaries are 16-aligned).
// ---------------------------------------------------------------------------
template <bool OUTBF, bool GELU, bool RES, bool QKVS>
__global__ __launch_bounds__(256)
void gemm_bf16(const short* __restrict__ A, const short* __restrict__ Bt,
               const float* __restrict__ bias, const float* __restrict__ R,
               void* __restrict__ C, short* __restrict__ C2,
               short* __restrict__ C3, int M, int N, int K) {
  __shared__ short As[128 * 64];
  __shared__ short Bs[128 * 64];
  const int t = threadIdx.x, lane = t & 63, w = t >> 6;
  const int g = lane >> 4, la = lane & 15;
  const int bn = blockIdx.x, bm = blockIdx.y;
  const int wm = w >> 1, wn = w & 1;

  const int srow = t >> 3;
  const int scolb = ((t & 7) * 16) ^ ((srow & 7) << 4);  // pre-swizzled byte col
  const short* Ag = A + (size_t)(bm * 128 + srow) * K + (scolb >> 1);
  const short* Bg = Bt + (size_t)(bn * 128 + srow) * K + (scolb >> 1);
  short* Asl = As + t * 8;
  short* Bsl = Bs + t * 8;

  f32x4 acc[4][4];
  #pragma unroll
  for (int i = 0; i < 4; ++i)
    #pragma unroll
    for (int j = 0; j < 4; ++j) acc[i][j] = (f32x4){0.f, 0.f, 0.f, 0.f};

  const int KT = K >> 6;
  for (int kt = 0; kt < KT; ++kt) {
    __syncthreads();
    #pragma unroll
    for (int i = 0; i < 4; ++i) {
      gl16(Ag + (size_t)i * 32 * K + kt * 64, Asl + i * 2048);
      gl16(Bg + (size_t)i * 32 * K + kt * 64, Bsl + i * 2048);
    }
    __syncthreads();
    #pragma unroll
    for (int ks = 0; ks < 2; ++ks) {
      bf16x8 af[4], bfr[4];
      #pragma unroll
      for (int mi = 0; mi < 4; ++mi) {
        const int row = wm * 64 + mi * 16 + la;
        af[mi] = *(const bf16x8*)((const char*)As + row * 128 +
                                  ((ks * 64 + g * 16) ^ ((row & 7) << 4)));
      }
      #pragma unroll
      for (int ni = 0; ni < 4; ++ni) {
        const int row = wn * 64 + ni * 16 + la;
        bfr[ni] = *(const bf16x8*)((const char*)Bs + row * 128 +
                                   ((ks * 64 + g * 16) ^ ((row & 7) << 4)));
      }
      #pragma unroll
      for (int mi = 0; mi < 4; ++mi)
        #pragma unroll
        for (int ni = 0; ni < 4; ++ni)
          acc[mi][ni] = __builtin_amdgcn_mfma_f32_16x16x32_bf16(
              af[mi], bfr[ni], acc[mi][ni], 0, 0, 0);
    }
  }

  const int crow0 = bm * 128 + wm * 64 + g * 4;
  const int ccol0 = bn * 128 + wn * 64 + la;
  float bl[4];
  #pragma unroll
  for (int ni = 0; ni < 4; ++ni) bl[ni] = bias[ccol0 + ni * 16];
  #pragma unroll
  for (int mi = 0; mi < 4; ++mi) {
    #pragma unroll
    for (int r = 0; r < 4; ++r) {
      const int row = crow0 + mi * 16 + r;
      if (QKVS) {
        const int bq = row >> 11, s = row & 2047;   // SEQ=2048
        #pragma unroll
        for (int ni = 0; ni < 4; ++ni) {
          const int n = ccol0 + ni * 16;
          const int region = n >> 10;               // 0=Q 1=K 2=V
          const int nn = n & 1023;
          short* dst = region == 0 ? (short*)C : (region == 1 ? C2 : C3);
          dst[((size_t)(bq * NHEAD + (nn >> 6)) * SEQ + s) * 64 + (nn & 63)] =
              (short)f2b(acc[mi][ni][r] + bl[ni]);
        }
      } else {
        #pragma unroll
        for (int ni = 0; ni < 4; ++ni) {
          float v = acc[mi][ni][r] + bl[ni];
          if (GELU) v = gelu_new_f(v);
          if (RES) v += R[(size_t)row * N + ccol0 + ni * 16];
          if (OUTBF)
            ((short*)C)[(size_t)row * N + ccol0 + ni * 16] = (short)f2b(v);
          else
            ((float*)C)[(size_t)row * N + ccol0 + ni * 16] = v;
        }
      }
    }
  }
}

// ---------------------------------------------------------------------------
// V transpose: Vb bf16 [b][h][s][64] -> Vtb bf16 [b][h][64][s] (LDS tile).
// ---------------------------------------------------------------------------
__global__ __launch_bounds__(256)
void prepv_kernel(const short* __restrict__ Vb, short* __restrict__ Vtb) {
  const int st = blockIdx.x, h = blockIdx.y, b = blockIdx.z;
  const int t = threadIdx.x;
  const int s0 = st * 64;
  const size_t bh = (size_t)b * NHEAD + h;
  __shared__ short vt[64][72];
  #pragma unroll
  for (int i = 0; i < 2; ++i) {
    const int cc = t + i * 256;
    const int r = cc >> 3, d8 = (cc & 7) * 8;
    bf16x8 v8 = *(const bf16x8*)(Vb + (bh * SEQ + s0 + r) * 64 + d8);
    #pragma unroll
    for (int j = 0; j < 8; ++j) vt[d8 + j][r] = v8[j];
  }
  __syncthreads();
  #pragma unroll
  for (int i = 0; i < 2; ++i) {
    const int cc = t + i * 256;
    const int d = cc >> 3, s8 = (cc & 7) * 8;
    bf16x8 vv;
    #pragma unroll
    for (int j = 0; j < 8; ++j) vv[j] = vt[d][s8 + j];
    *(bf16x8*)(Vtb + (bh * 64 + d) * SEQ + s0 + s8) = vv;
  }
}

// ---------------------------------------------------------------------------
// bf16 MFMA causal flash attention, log2-domain softmax, DOUBLE-BUFFERED.
// Block = paired q-tiles (p, QT-1-p), flattened over both: exactly QT+1
// K-tile iterations. Per iteration: STAGE(next tile -> buf^1) overlaps
// {QK, softmax, PV} on buf; single __syncthreads() (its vmcnt(0)+lgkmcnt(0)
// drain is the staging/read fence); swap. T5 setprio around MFMA clusters.
// Defer-max (T13): skip O-rescale when tile max <= m + 11.5 (log2 domain).
// ---------------------------------------------------------------------------
__global__ __launch_bounds__(256)
void mha_kernel(const short* __restrict__ Qb, const short* __restrict__ Kb,
                const short* __restrict__ Vtb, short* __restrict__ out) {
  const int p = blockIdx.x, h = blockIdx.y, b = blockIdx.z;
  const int t = threadIdx.x, lane = t & 63, w = t >> 6;
  const int g = lane >> 4, la = lane & 15;
  const size_t bh = (size_t)b * NHEAD + h;

  __shared__ short Ks[2][64 * 64];
  __shared__ short Vts[2][64 * 64];
  __shared__ short Ps[4][16 * 64];

  const int srow = t >> 3;
  const int scolb = ((t & 7) * 16) ^ ((srow & 7) << 4);  // pre-swizzled

  const int qt0 = p, qt1 = QT - 1 - p;
  const int T0 = qt0 + 1, total = T0 + qt1 + 1;

  int qt = qt0;
  const short* qr = Qb + (bh * SEQ + (size_t)qt0 * 64 + w * 16 + la) * 64;
  bf16x8 qf0 = *(const bf16x8*)(qr + g * 8);
  bf16x8 qf1 = *(const bf16x8*)(qr + 32 + g * 8);

  float o[16];
  #pragma unroll
  for (int i = 0; i < 16; ++i) o[i] = 0.f;
  float m = -1e30f, l = 0.f;

  // prologue: stage tile it=0 (k0=0) into buf 0
  #pragma unroll
  for (int i = 0; i < 2; ++i) {
    const int r = srow + i * 32;
    gl16(Kb + (bh * SEQ + r) * 64 + (scolb >> 1), Ks[0] + i * 2048 + t * 8);
    gl16(Vtb + (bh * 64 + r) * SEQ + (scolb >> 1), Vts[0] + i * 2048 + t * 8);
  }
  __syncthreads();  // vmcnt(0) drain: tile 0 resident

  int cur = 0;
  #pragma unroll 1
  for (int it = 0; it < total; ++it) {
    // issue next tile's staging early (hidden under QK/softmax/PV)
    if (it + 1 < total) {
      const int nkt = (it + 1 < T0) ? (it + 1) : (it + 1 - T0);
      const int nk0 = nkt * 64;
      #pragma unroll
      for (int i = 0; i < 2; ++i) {
        const int r = srow + i * 32;
        gl16(Kb + (bh * SEQ + nk0 + r) * 64 + (scolb >> 1),
             Ks[cur ^ 1] + i * 2048 + t * 8);
        gl16(Vtb + (bh * 64 + r) * SEQ + nk0 + (scolb >> 1),
             Vts[cur ^ 1] + i * 2048 + t * 8);
      }
    }

    // === QK^T on buf[cur] ===
    float sv[16];
    __builtin_amdgcn_s_setprio(1);
    #pragma unroll
    for (int mt = 0; mt < 4; ++mt) {
      const int ar = mt * 16 + la;
      const int ab = ar * 128 + ((g * 16) ^ ((ar & 7) << 4));
      bf16x8 ka0 = *(const bf16x8*)((char*)Ks[cur] + ab);
      bf16x8 ka1 = *(const bf16x8*)((char*)Ks[cur] + (ab ^ 64));
      f32x4 sa = {0.f, 0.f, 0.f, 0.f};
      sa = __builtin_amdgcn_mfma_f32_16x16x32_bf16(ka0, qf0, sa, 0, 0, 0);
      sa = __builtin_amdgcn_mfma_f32_16x16x32_bf16(ka1, qf1, sa, 0, 0, 0);
      sv[mt * 4 + 0] = sa[0]; sv[mt * 4 + 1] = sa[1];
      sv[mt * 4 + 2] = sa[2]; sv[mt * 4 + 3] = sa[3];
    }
    __builtin_amdgcn_s_setprio(0);

    const bool diag = (it == T0 - 1) || (it == total - 1);
    if (diag) {  // causal mask (log2 domain: -10000*log2e)
      const int qrel = w * 16 + la;
      #pragma unroll
      for (int idx = 0; idx < 16; ++idx) {
        const int krel = (idx >> 2) * 16 + g * 4 + (idx & 3);
        if (krel > qrel) sv[idx] = -14426.950408889634f;
      }
    }

    // tree max over 16, then cross-g (lanes share la -> per-q-row max)
    float t8[8], t4[4], t2[2];
    #pragma unroll
    for (int i = 0; i < 8; ++i) t8[i] = fmaxf(sv[2 * i], sv[2 * i + 1]);
    #pragma unroll
    for (int i = 0; i < 4; ++i) t4[i] = fmaxf(t8[2 * i], t8[2 * i + 1]);
    t2[0] = fmaxf(t4[0], t4[1]); t2[1] = fmaxf(t4[2], t4[3]);
    float tmax = fmaxf(t2[0], t2[1]);
    tmax = fmaxf(tmax, __shfl_xor(tmax, 16));
    tmax = fmaxf(tmax, __shfl_xor(tmax, 32));

    const bool skip = __all(tmax <= m + 11.5f) != 0;  // defer-max (T13)
    const float mn = skip ? m : fmaxf(m, tmax);

    float ss8[8], ss4[4];
    #pragma unroll
    for (int i = 0; i < 16; ++i) sv[i] = exp2f(sv[i] - mn);
    #pragma unroll
    for (int i = 0; i < 8; ++i) ss8[i] = sv[2 * i] + sv[2 * i + 1];
    #pragma unroll
    for (int i = 0; i < 4; ++i) ss4[i] = ss8[2 * i] + ss8[2 * i + 1];
    float ps = (ss4[0] + ss4[1]) + (ss4[2] + ss4[3]);
    ps += __shfl_xor(ps, 16);
    ps += __shfl_xor(ps, 32);

    if (skip) {
      l += ps;
    } else {
      const float sc = exp2f(m - mn);
      l = l * sc + ps;
      m = mn;
      #pragma unroll
      for (int r = 0; r < 4; ++r) {
        const float scr = __shfl(sc, (g << 2) + r);
        o[r] *= scr; o[4 + r] *= scr; o[8 + r] *= scr; o[12 + r] *= scr;
      }
    }

    // write P (bf16) to per-wave swizzled LDS
    #pragma unroll
    for (int mt = 0; mt < 4; ++mt) {
      #pragma unroll
      for (int r2 = 0; r2 < 2; ++r2) {
        const unsigned pk = (unsigned)f2b(sv[mt * 4 + r2 * 2]) |
                            ((unsigned)f2b(sv[mt * 4 + r2 * 2 + 1]) << 16);
        const int kk = mt * 16 + g * 4 + r2 * 2;
        const int pb = la * 128 + ((kk * 2) ^ ((la & 7) << 4));
        *(unsigned*)((char*)Ps[w] + pb) = pk;
      }
    }
    // same-wave cross-lane LDS RAW hazard: drain + pin (rule #18);
    // gl16 staging uses vmcnt, NOT lgkmcnt -> stays in flight.
    asm volatile("s_waitcnt lgkmcnt(0)" ::: "memory");
    __builtin_amdgcn_sched_barrier(0);

    const int pb0 = la * 128 + ((g * 16) ^ ((la & 7) << 4));
    const bf16x8 pa0 = *(const bf16x8*)((char*)Ps[w] + pb0);
    const bf16x8 pa1 = *(const bf16x8*)((char*)Ps[w] + (pb0 ^ 64));
    __builtin_amdgcn_s_setprio(1);
    #pragma unroll
    for (int nt = 0; nt < 4; ++nt) {
      const int dr = nt * 16 + la;
      const int vb = dr * 128 + ((g * 16) ^ ((dr & 7) << 4));
      bf16x8 vb0 = *(const bf16x8*)((char*)Vts[cur] + vb);
      bf16x8 vb1 = *(const bf16x8*)((char*)Vts[cur] + (vb ^ 64));
      f32x4 oa = {o[nt * 4 + 0], o[nt * 4 + 1], o[nt * 4 + 2], o[nt * 4 + 3]};
      oa = __builtin_amdgcn_mfma_f32_16x16x32_bf16(pa0, vb0, oa, 0, 0, 0);
      oa = __builtin_amdgcn_mfma_f32_16x16x32_bf16(pa1, vb1, oa, 0, 0, 0);
      o[nt * 4 + 0] = oa[0]; o[nt * 4 + 1] = oa[1];
      o[nt * 4 + 2] = oa[2]; o[nt * 4 + 3] = oa[3];
    }
    __builtin_amdgcn_s_setprio(0);

    if (diag) {  // finished a q-tile: write output (and reset for e=1)
      const float linv = 1.f / l;
      #pragma unroll
      for (int r = 0; r < 4; ++r) {
        const float li = __shfl(linv, (g << 2) + r);
        const int qrow_g = qt * 64 + w * 16 + g * 4 + r;
        #pragma unroll
        for (int nt = 0; nt < 4; ++nt) {
          out[((size_t)b * SEQ + qrow_g) * DMODEL + h * 64 + nt * 16 + la] =
              (short)f2b(o[nt * 4 + r] * li);
        }
      }
      if (it == T0 - 1) {
        #pragma unroll
        for (int i = 0; i < 16; ++i) o[i] = 0.f;
        m = -1e30f; l = 0.f;
        qt = qt1;
        const short* qr1 = Qb + (bh * SEQ + (size_t)qt1 * 64 + w * 16 + la) * 64;
        qf0 = *(const bf16x8*)(qr1 + g * 8);
        qf1 = *(const bf16x8*)(qr1 + 32 + g * 8);
      }
    }

    __syncthreads();  // vmcnt(0)+lgkmcnt(0): next tile resident, reads done
    cur ^= 1;
  }
}

// ---------------------------------------------------------------------------
// Launcher
// ---------------------------------------------------------------------------
extern "C" void kernel_launch(void* const* d_in, const int* in_sizes, int n_in,
                              void* d_out, int out_size, void* d_ws, size_t ws_size,
                              hipStream_t stream) {
  const float* hidden      = (const float*)d_in[0];
  const float* ln1_g       = (const float*)d_in[1];
  const float* ln1_b       = (const float*)d_in[2];
  const float* w_attn      = (const float*)d_in[3];
  const float* b_attn      = (const float*)d_in[4];
  const float* w_attn_proj = (const float*)d_in[5];
  const float* b_attn_proj = (const float*)d_in[6];
  const float* ln2_g       = (const float*)d_in[7];
  const float* ln2_b       = (const float*)d_in[8];
  const float* w_fc        = (const float*)d_in[9];
  const float* b_fc        = (const float*)d_in[10];
  const float* w_mlp_proj  = (const float*)d_in[11];
  const float* b_mlp_proj  = (const float*)d_in[12];
  float* out = (float*)d_out;

  const int Bn = in_sizes[0] / (SEQ * DMODEL);  // batch (=4)
  const int M = Bn * SEQ;                        // 8192 rows

  // Workspace layout (bytes, ~210MB):
  char* W = (char*)d_ws;
  const size_t szMD2 = (size_t)M * DMODEL * 2;        // 16.8MB
  short* xln_b  = (short*)W;                          // LN out
  short* Vb     = (short*)(W + szMD2);                // V [bh][s][64] (attn phase)
  short* a1_b   = Vb;                                 // later: FF acts [M,FF] bf16
  char*  p2     = W + szMD2 + (size_t)M * FFDIM * 2;
  short* Qb     = (short*)p2;
  short* Kb     = Qb + (size_t)M * DMODEL;
  short* Vtb    = Kb + (size_t)M * DMODEL;
  short* attn_b = Vtb + (size_t)M * DMODEL;
  float* h2     = (float*)(p2 + 4 * szMD2);
  short* wat    = (short*)(p2 + 4 * szMD2 + (size_t)M * DMODEL * 4);
  short* wpt    = wat + (size_t)3 * DMODEL * DMODEL;
  short* wft    = wpt + (size_t)DMODEL * DMODEL;
  short* wmt    = wft + (size_t)FFDIM * DMODEL;
  float* bas    = (float*)(wmt + (size_t)DMODEL * FFDIM);  // scaled b_attn

  // 0. fused weight convert+transpose (+ bias prescale block)
  wconv4_kernel<<<3073, 256, 0, stream>>>(w_attn, wat, w_attn_proj, wpt,
                                          w_fc, wft, w_mlp_proj, wmt,
                                          b_attn, bas);
  // 1. LN1 -> bf16
  ln_kernel<<<M, 256, 0, stream>>>(hidden, ln1_g, ln1_b, xln_b);
  // 2. QKV GEMM, epilogue scatters Q/K/V to [b][h][s][64] (Q pre-scaled)
  gemm_bf16<true, false, false, true>
      <<<dim3(3 * DMODEL / 128, M / 128), 256, 0, stream>>>(
      xln_b, wat, bas, nullptr, Qb, Kb, Vb, M, 3 * DMODEL, DMODEL);
  // 2.5 V transpose only
  prepv_kernel<<<dim3(SEQ / 64, NHEAD, Bn), 256, 0, stream>>>(Vb, Vtb);
  // 3. attention -> bf16 [M,1024]  (paired q-tiles, double-buffered)
  mha_kernel<<<dim3(QT / 2, NHEAD, Bn), 256, 0, stream>>>(Qb, Kb, Vtb, attn_b);
  // 4. h2 = hidden + attn @ w_attn_proj + b   (fp32)
  gemm_bf16<false, false, true, false>
      <<<dim3(DMODEL / 128, M / 128), 256, 0, stream>>>(
      attn_b, wpt, b_attn_proj, hidden, h2, nullptr, nullptr, M, DMODEL, DMODEL);
  // 5. LN2 -> bf16
  ln_kernel<<<M, 256, 0, stream>>>(h2, ln2_g, ln2_b, xln_b);
  // 6. a1 = gelu(xln2 @ w_fc + b) -> bf16 [M,4096]  (overwrites dead Vb)
  gemm_bf16<true, true, false, false>
      <<<dim3(FFDIM / 128, M / 128), 256, 0, stream>>>(
      xln_b, wft, b_fc, nullptr, a1_b, nullptr, nullptr, M, FFDIM, DMODEL);
  // 7. out = h2 + a1 @ w_mlp_proj + b  (fp32)
  gemm_bf16<false, false, true, false>
      <<<dim3(DMODEL / 128, M / 128), 256, 0, stream>>>(
      a1_b, wmt, b_mlp_proj, h2, out, nullptr, nullptr, M, DMODEL, FFDIM);
}

// Round 8
// 507.175 us; speedup vs baseline: 17.5205x; 1.0902x over previous
//
#include <hip/hip_runtime.h>
#include <hip/hip_bf16.h>
#include <cstddef>

// GPT-2 block. B=4 (derived), S=2048, D=1024, H=16, DH=64, FF=4096.
#define SEQ   2048
#define DMODEL 1024
#define NHEAD 16
#define HDIM  64
#define FFDIM 4096
#define QT    (SEQ / 64)   // 32 q-tiles

typedef __attribute__((ext_vector_type(8))) short bf16x8;
typedef __attribute__((ext_vector_type(4))) short bf16x4;
typedef __attribute__((ext_vector_type(4))) float f32x4;

#define QSCALE (0.125f * 1.44269504088896f)  // 1/sqrt(64) * log2(e)

__device__ __forceinline__ unsigned short f2b(float x) {
  __hip_bfloat16 h = __float2bfloat16(x);
  return __builtin_bit_cast(unsigned short, h);
}
__device__ __forceinline__ float b2f(short u) {
  unsigned x = ((unsigned)(unsigned short)u) << 16;
  return __builtin_bit_cast(float, x);
}
// async global->LDS, 16B per lane. LDS dest = wave-uniform base + lane*16.
__device__ __forceinline__ void gl16(const short* g, short* l) {
  __builtin_amdgcn_global_load_lds(
      (const __attribute__((address_space(1))) void*)g,
      (__attribute__((address_space(3))) void*)l, 16, 0, 0);
}

// ---------------------------------------------------------------------------
// LayerNorm: one block per row, 256 threads, float4/thread; bf16 output.
// ---------------------------------------------------------------------------
__global__ __launch_bounds__(256)
void ln_kernel(const float* __restrict__ x, const float* __restrict__ g,
               const float* __restrict__ b, short* __restrict__ y) {
  const int row = blockIdx.x;
  const int t = threadIdx.x;
  const float* xr = x + (size_t)row * DMODEL;
  float4 v = *(const float4*)(xr + t * 4);
  float s = v.x + v.y + v.z + v.w;
  float q = v.x * v.x + v.y * v.y + v.z * v.z + v.w * v.w;
  #pragma unroll
  for (int off = 32; off; off >>= 1) {
    s += __shfl_xor(s, off);
    q += __shfl_xor(q, off);
  }
  __shared__ float ss[4], qq[4];
  if ((t & 63) == 0) { ss[t >> 6] = s; qq[t >> 6] = q; }
  __syncthreads();
  s = ss[0] + ss[1] + ss[2] + ss[3];
  q = qq[0] + qq[1] + qq[2] + qq[3];
  const float mean = s * (1.f / DMODEL);
  const float var = q * (1.f / DMODEL) - mean * mean;
  const float rstd = rsqrtf(var + 1e-5f);
  float4 gv = *(const float4*)(g + t * 4);
  float4 bv = *(const float4*)(b + t * 4);
  bf16x4 o;
  o[0] = (short)f2b((v.x - mean) * rstd * gv.x + bv.x);
  o[1] = (short)f2b((v.y - mean) * rstd * gv.y + bv.y);
  o[2] = (short)f2b((v.z - mean) * rstd * gv.z + bv.z);
  o[3] = (short)f2b((v.w - mean) * rstd * gv.w + bv.w);
  *(bf16x4*)(y + (size_t)row * DMODEL + t * 4) = o;
}

// ---------------------------------------------------------------------------
// GELU (GPT-2 'gelu_new')
// ---------------------------------------------------------------------------
__device__ __forceinline__ float gelu_new_f(float x) {
  const float c = 0.7978845608028654f;  // sqrt(2/pi)
  float u = c * (x + 0.044715f * x * x * x);
  float e = __expf(2.f * u);
  float t = 1.f - 2.f / (e + 1.f);
  return 0.5f * x * (1.f + t);
}

// ---------------------------------------------------------------------------
// Fused weight convert+transpose (fp32 [K][N] -> bf16 [N][K]) for 4 weights.
// Q-columns (n<1024) of w_attn pre-scaled by QSCALE. Block 3072 scales b_attn.
// ---------------------------------------------------------------------------
__global__ __launch_bounds__(256)
void wconv4_kernel(const float* __restrict__ w0, short* __restrict__ t0,
                   const float* __restrict__ w1, short* __restrict__ t1,
                   const float* __restrict__ w2, short* __restrict__ t2,
                   const float* __restrict__ w3, short* __restrict__ t3,
                   const float* __restrict__ ba, float* __restrict__ bas) {
  int id = blockIdx.x;
  const int t = threadIdx.x;
  if (id == 3072) {  // bias pre-scale for the QKV GEMM
    #pragma unroll
    for (int i = t; i < 3072; i += 256)
      bas[i] = ba[i] * (i < 1024 ? QSCALE : 1.f);
    return;
  }
  const float* W; short* Wt; int K, N;
  float sc = 1.f;
  if (id < 768)       { W = w0; Wt = t0; K = 1024; N = 3072; }
  else if (id < 1024) { id -= 768;  W = w1; Wt = t1; K = 1024; N = 1024; }
  else if (id < 2048) { id -= 1024; W = w2; Wt = t2; K = 1024; N = 4096; }
  else                { id -= 2048; W = w3; Wt = t3; K = 4096; N = 1024; }
  const int nt = N >> 6;
  const int n0 = (id % nt) * 64, k0 = (id / nt) * 64;
  if (W == w0 && n0 < 1024) sc = QSCALE;  // Q column block
  __shared__ short tile[64][72];
  #pragma unroll
  for (int i = 0; i < 4; ++i) {
    const int row = i * 16 + (t >> 4);      // k within tile
    const int col4 = (t & 15) * 4;          // n within tile
    float4 v = *(const float4*)(W + (size_t)(k0 + row) * N + n0 + col4);
    tile[col4 + 0][row] = (short)f2b(v.x * sc);
    tile[col4 + 1][row] = (short)f2b(v.y * sc);
    tile[col4 + 2][row] = (short)f2b(v.z * sc);
    tile[col4 + 3][row] = (short)f2b(v.w * sc);
  }
  __syncthreads();
  #pragma unroll
  for (int i = 0; i < 2; ++i) {
    const int cc = t + i * 256;
    const int nr = cc >> 3, k8 = (cc & 7) * 8;
    bf16x8 vv;
    #pragma unroll
    for (int j = 0; j < 8; ++j) vv[j] = tile[nr][k8 + j];
    *(bf16x8*)(Wt + (size_t)(n0 + nr) * K + k0 + k8) = vv;
  }
}

// ---------------------------------------------------------------------------
// bf16 MFMA GEMM: C[M,N] = A[M,K](bf16) @ Bt[N,K](bf16)^T + bias (+R fp32)
// 128x128 tile, BK=64, 4 waves, mfma_f32_16x16x32_bf16.
// 2-PHASE DOUBLE-BUFFER (T3-minimum, validated in mha R7): issue next tile's
// global_load_lds BEFORE computing current, one __syncthreads()/iter (its
// vmcnt(0) drain lands after compute -> staging latency partially hidden).
// 1-D grid + XCD-aware bijective swizzle (T1): nwg%8==0 for all our shapes.
// QKVS: epilogue scatters Q/K/V to per-head [b][h][s][64] (C,C2,C3).
// ---------------------------------------------------------------------------
template <bool OUTBF, bool GELU, bool RES, bool QKVS>
__global__ __launch_bounds__(256)
void gemm_bf16(const short* __restrict__ A, const short* __restrict__ Bt,
               const float* __restrict__ bias, const float* __restrict__ R,
               void* __restrict__ C, short* __restrict__ C2,
               short* __restrict__ C3, int M, int N, int K, int nbn) {
  __shared__ short As[2][128 * 64];
  __shared__ short Bs[2][128 * 64];
  const int t = threadIdx.x, lane = t & 63, w = t >> 6;
  const int g = lane >> 4, la = lane & 15;
  // XCD swizzle: consecutive swz ids land on one XCD -> A-panel L2 locality
  const int cpx = gridDim.x >> 3;
  const int swz = (blockIdx.x & 7) * cpx + (blockIdx.x >> 3);
  const int bn = swz % nbn, bm = swz / nbn;
  const int wm = w >> 1, wn = w & 1;

  const int srow = t >> 3;
  const int scolb = ((t & 7) * 16) ^ ((srow & 7) << 4);  // pre-swizzled byte col
  const short* Ag = A + (size_t)(bm * 128 + srow) * K + (scolb >> 1);
  const short* Bg = Bt + (size_t)(bn * 128 + srow) * K + (scolb >> 1);

  f32x4 acc[4][4];
  #pragma unroll
  for (int i = 0; i < 4; ++i)
    #pragma unroll
    for (int j = 0; j < 4; ++j) acc[i][j] = (f32x4){0.f, 0.f, 0.f, 0.f};

  const int KT = K >> 6;
  // prologue: stage tile 0 into buf 0
  #pragma unroll
  for (int i = 0; i < 4; ++i) {
    gl16(Ag + (size_t)i * 32 * K, As[0] + i * 2048 + t * 8);
    gl16(Bg + (size_t)i * 32 * K, Bs[0] + i * 2048 + t * 8);
  }
  __syncthreads();  // vmcnt(0): tile 0 resident for all waves

  int cur = 0;
  #pragma unroll 1
  for (int kt = 0; kt < KT; ++kt) {
    if (kt + 1 < KT) {  // stage next tile early; hidden under compute
      #pragma unroll
      for (int i = 0; i < 4; ++i) {
        gl16(Ag + (size_t)i * 32 * K + (kt + 1) * 64,
             As[cur ^ 1] + i * 2048 + t * 8);
        gl16(Bg + (size_t)i * 32 * K + (kt + 1) * 64,
             Bs[cur ^ 1] + i * 2048 + t * 8);
      }
    }
    #pragma unroll
    for (int ks = 0; ks < 2; ++ks) {
      bf16x8 af[4], bfr[4];
      #pragma unroll
      for (int mi = 0; mi < 4; ++mi) {
        const int row = wm * 64 + mi * 16 + la;
        af[mi] = *(const bf16x8*)((const char*)As[cur] + row * 128 +
                                  ((ks * 64 + g * 16) ^ ((row & 7) << 4)));
      }
      #pragma unroll
      for (int ni = 0; ni < 4; ++ni) {
        const int row = wn * 64 + ni * 16 + la;
        bfr[ni] = *(const bf16x8*)((const char*)Bs[cur] + row * 128 +
                                   ((ks * 64 + g * 16) ^ ((row & 7) << 4)));
      }
      #pragma unroll
      for (int mi = 0; mi < 4; ++mi)
        #pragma unroll
        for (int ni = 0; ni < 4; ++ni)
          acc[mi][ni] = __builtin_amdgcn_mfma_f32_16x16x32_bf16(
              af[mi], bfr[ni], acc[mi][ni], 0, 0, 0);
    }
    __syncthreads();  // vmcnt(0)+lgkmcnt(0): next tile resident, reads done
    cur ^= 1;
  }

  const int crow0 = bm * 128 + wm * 64 + g * 4;
  const int ccol0 = bn * 128 + wn * 64 + la;
  float bl[4];
  #pragma unroll
  for (int ni = 0; ni < 4; ++ni) bl[ni] = bias[ccol0 + ni * 16];
  #pragma unroll
  for (int mi = 0; mi < 4; ++mi) {
    #pragma unroll
    for (int r = 0; r < 4; ++r) {
      const int row = crow0 + mi * 16 + r;
      if (QKVS) {
        const int bq = row >> 11, s = row & 2047;   // SEQ=2048
        #pragma unroll
        for (int ni = 0; ni < 4; ++ni) {
          const int n = ccol0 + ni * 16;
          const int region = n >> 10;               // 0=Q 1=K 2=V
          const int nn = n & 1023;
          short* dst = region == 0 ? (short*)C : (region == 1 ? C2 : C3);
          dst[((size_t)(bq * NHEAD + (nn >> 6)) * SEQ + s) * 64 + (nn & 63)] =
              (short)f2b(acc[mi][ni][r] + bl[ni]);
        }
      } else {
        #pragma unroll
        for (int ni = 0; ni < 4; ++ni) {
          float v = acc[mi][ni][r] + bl[ni];
          if (GELU) v = gelu_new_f(v);
          if (RES) v += R[(size_t)row * N + ccol0 + ni * 16];
          if (OUTBF)
            ((short*)C)[(size_t)row * N + ccol0 + ni * 16] = (short)f2b(v);
          else
            ((float*)C)[(size_t)row * N + ccol0 + ni * 16] = v;
        }
      }
    }
  }
}

// ---------------------------------------------------------------------------
// V transpose: Vb bf16 [b][h][s][64] -> Vtb bf16 [b][h][64][s] (LDS tile).
// ---------------------------------------------------------------------------
__global__ __launch_bounds__(256)
void prepv_kernel(const short* __restrict__ Vb, short* __restrict__ Vtb) {
  const int st = blockIdx.x, h = blockIdx.y, b = blockIdx.z;
  const int t = threadIdx.x;
  const int s0 = st * 64;
  const size_t bh = (size_t)b * NHEAD + h;
  __shared__ short vt[64][72];
  #pragma unroll
  for (int i = 0; i < 2; ++i) {
    const int cc = t + i * 256;
    const int r = cc >> 3, d8 = (cc & 7) * 8;
    bf16x8 v8 = *(const bf16x8*)(Vb + (bh * SEQ + s0 + r) * 64 + d8);
    #pragma unroll
    for (int j = 0; j < 8; ++j) vt[d8 + j][r] = v8[j];
  }
  __syncthreads();
  #pragma unroll
  for (int i = 0; i < 2; ++i) {
    const int cc = t + i * 256;
    const int d = cc >> 3, s8 = (cc & 7) * 8;
    bf16x8 vv;
    #pragma unroll
    for (int j = 0; j < 8; ++j) vv[j] = vt[d][s8 + j];
    *(bf16x8*)(Vtb + (bh * 64 + d) * SEQ + s0 + s8) = vv;
  }
}

// ---------------------------------------------------------------------------
// bf16 MFMA causal flash attention (validated R7): paired q-tiles,
// double-buffered staging, log2-domain softmax, defer-max, setprio.
// ---------------------------------------------------------------------------
__global__ __launch_bounds__(256)
void mha_kernel(const short* __restrict__ Qb, const short* __restrict__ Kb,
                const short* __restrict__ Vtb, short* __restrict__ out) {
  const int p = blockIdx.x, h = blockIdx.y, b = blockIdx.z;
  const int t = threadIdx.x, lane = t & 63, w = t >> 6;
  const int g = lane >> 4, la = lane & 15;
  const size_t bh = (size_t)b * NHEAD + h;

  __shared__ short Ks[2][64 * 64];
  __shared__ short Vts[2][64 * 64];
  __shared__ short Ps[4][16 * 64];

  const int srow = t >> 3;
  const int scolb = ((t & 7) * 16) ^ ((srow & 7) << 4);  // pre-swizzled

  const int qt0 = p, qt1 = QT - 1 - p;
  const int T0 = qt0 + 1, total = T0 + qt1 + 1;

  int qt = qt0;
  const short* qr = Qb + (bh * SEQ + (size_t)qt0 * 64 + w * 16 + la) * 64;
  bf16x8 qf0 = *(const bf16x8*)(qr + g * 8);
  bf16x8 qf1 = *(const bf16x8*)(qr + 32 + g * 8);

  float o[16];
  #pragma unroll
  for (int i = 0; i < 16; ++i) o[i] = 0.f;
  float m = -1e30f, l = 0.f;

  // prologue: stage tile it=0 (k0=0) into buf 0
  #pragma unroll
  for (int i = 0; i < 2; ++i) {
    const int r = srow + i * 32;
    gl16(Kb + (bh * SEQ + r) * 64 + (scolb >> 1), Ks[0] + i * 2048 + t * 8);
    gl16(Vtb + (bh * 64 + r) * SEQ + (scolb >> 1), Vts[0] + i * 2048 + t * 8);
  }
  __syncthreads();  // vmcnt(0) drain: tile 0 resident

  int cur = 0;
  #pragma unroll 1
  for (int it = 0; it < total; ++it) {
    // issue next tile's staging early (hidden under QK/softmax/PV)
    if (it + 1 < total) {
      const int nkt = (it + 1 < T0) ? (it + 1) : (it + 1 - T0);
      const int nk0 = nkt * 64;
      #pragma unroll
      for (int i = 0; i < 2; ++i) {
        const int r = srow + i * 32;
        gl16(Kb + (bh * SEQ + nk0 + r) * 64 + (scolb >> 1),
             Ks[cur ^ 1] + i * 2048 + t * 8);
        gl16(Vtb + (bh * 64 + r) * SEQ + nk0 + (scolb >> 1),
             Vts[cur ^ 1] + i * 2048 + t * 8);
      }
    }

    // === QK^T on buf[cur] ===
    float sv[16];
    __builtin_amdgcn_s_setprio(1);
    #pragma unroll
    for (int mt = 0; mt < 4; ++mt) {
      const int ar = mt * 16 + la;
      const int ab = ar * 128 + ((g * 16) ^ ((ar & 7) << 4));
      bf16x8 ka0 = *(const bf16x8*)((char*)Ks[cur] + ab);
      bf16x8 ka1 = *(const bf16x8*)((char*)Ks[cur] + (ab ^ 64));
      f32x4 sa = {0.f, 0.f, 0.f, 0.f};
      sa = __builtin_amdgcn_mfma_f32_16x16x32_bf16(ka0, qf0, sa, 0, 0, 0);
      sa = __builtin_amdgcn_mfma_f32_16x16x32_bf16(ka1, qf1, sa, 0, 0, 0);
      sv[mt * 4 + 0] = sa[0]; sv[mt * 4 + 1] = sa[1];
      sv[mt * 4 + 2] = sa[2]; sv[mt * 4 + 3] = sa[3];
    }
    __builtin_amdgcn_s_setprio(0);

    const bool diag = (it == T0 - 1) || (it == total - 1);
    if (diag) {  // causal mask (log2 domain: -10000*log2e)
      const int qrel = w * 16 + la;
      #pragma unroll
      for (int idx = 0; idx < 16; ++idx) {
        const int krel = (idx >> 2) * 16 + g * 4 + (idx & 3);
        if (krel > qrel) sv[idx] = -14426.950408889634f;
      }
    }

    // tree max over 16, then cross-g (lanes share la -> per-q-row max)
    float t8[8], t4[4], t2[2];
    #pragma unroll
    for (int i = 0; i < 8; ++i) t8[i] = fmaxf(sv[2 * i], sv[2 * i + 1]);
    #pragma unroll
    for (int i = 0; i < 4; ++i) t4[i] = fmaxf(t8[2 * i], t8[2 * i + 1]);
    t2[0] = fmaxf(t4[0], t4[1]); t2[1] = fmaxf(t4[2], t4[3]);
    float tmax = fmaxf(t2[0], t2[1]);
    tmax = fmaxf(tmax, __shfl_xor(tmax, 16));
    tmax = fmaxf(tmax, __shfl_xor(tmax, 32));

    const bool skip = __all(tmax <= m + 11.5f) != 0;  // defer-max (T13)
    const float mn = skip ? m : fmaxf(m, tmax);

    float ss8[8], ss4[4];
    #pragma unroll
    for (int i = 0; i < 16; ++i) sv[i] = exp2f(sv[i] - mn);
    #pragma unroll
    for (int i = 0; i < 8; ++i) ss8[i] = sv[2 * i] + sv[2 * i + 1];
    #pragma unroll
    for (int i = 0; i < 4; ++i) ss4[i] = ss8[2 * i] + ss8[2 * i + 1];
    float ps = (ss4[0] + ss4[1]) + (ss4[2] + ss4[3]);
    ps += __shfl_xor(ps, 16);
    ps += __shfl_xor(ps, 32);

    if (skip) {
      l += ps;
    } else {
      const float sc = exp2f(m - mn);
      l = l * sc + ps;
      m = mn;
      #pragma unroll
      for (int r = 0; r < 4; ++r) {
        const float scr = __shfl(sc, (g << 2) + r);
        o[r] *= scr; o[4 + r] *= scr; o[8 + r] *= scr; o[12 + r] *= scr;
      }
    }

    // write P (bf16) to per-wave swizzled LDS
    #pragma unroll
    for (int mt = 0; mt < 4; ++mt) {
      #pragma unroll
      for (int r2 = 0; r2 < 2; ++r2) {
        const unsigned pk = (unsigned)f2b(sv[mt * 4 + r2 * 2]) |
                            ((unsigned)f2b(sv[mt * 4 + r2 * 2 + 1]) << 16);
        const int kk = mt * 16 + g * 4 + r2 * 2;
        const int pb = la * 128 + ((kk * 2) ^ ((la & 7) << 4));
        *(unsigned*)((char*)Ps[w] + pb) = pk;
      }
    }
    // same-wave cross-lane LDS RAW hazard: drain + pin (rule #18);
    // gl16 staging uses vmcnt, NOT lgkmcnt -> stays in flight.
    asm volatile("s_waitcnt lgkmcnt(0)" ::: "memory");
    __builtin_amdgcn_sched_barrier(0);

    const int pb0 = la * 128 + ((g * 16) ^ ((la & 7) << 4));
    const bf16x8 pa0 = *(const bf16x8*)((char*)Ps[w] + pb0);
    const bf16x8 pa1 = *(const bf16x8*)((char*)Ps[w] + (pb0 ^ 64));
    __builtin_amdgcn_s_setprio(1);
    #pragma unroll
    for (int nt = 0; nt < 4; ++nt) {
      const int dr = nt * 16 + la;
      const int vb = dr * 128 + ((g * 16) ^ ((dr & 7) << 4));
      bf16x8 vb0 = *(const bf16x8*)((char*)Vts[cur] + vb);
      bf16x8 vb1 = *(const bf16x8*)((char*)Vts[cur] + (vb ^ 64));
      f32x4 oa = {o[nt * 4 + 0], o[nt * 4 + 1], o[nt * 4 + 2], o[nt * 4 + 3]};
      oa = __builtin_amdgcn_mfma_f32_16x16x32_bf16(pa0, vb0, oa, 0, 0, 0);
      oa = __builtin_amdgcn_mfma_f32_16x16x32_bf16(pa1, vb1, oa, 0, 0, 0);
      o[nt * 4 + 0] = oa[0]; o[nt * 4 + 1] = oa[1];
      o[nt * 4 + 2] = oa[2]; o[nt * 4 + 3] = oa[3];
    }
    __builtin_amdgcn_s_setprio(0);

    if (diag) {  // finished a q-tile: write output (and reset for e=1)
      const float linv = 1.f / l;
      #pragma unroll
      for (int r = 0; r < 4; ++r) {
        const float li = __shfl(linv, (g << 2) + r);
        const int qrow_g = qt * 64 + w * 16 + g * 4 + r;
        #pragma unroll
        for (int nt = 0; nt < 4; ++nt) {
          out[((size_t)b * SEQ + qrow_g) * DMODEL + h * 64 + nt * 16 + la] =
              (short)f2b(o[nt * 4 + r] * li);
        }
      }
      if (it == T0 - 1) {
        #pragma unroll
        for (int i = 0; i < 16; ++i) o[i] = 0.f;
        m = -1e30f; l = 0.f;
        qt = qt1;
        const short* qr1 = Qb + (bh * SEQ + (size_t)qt1 * 64 + w * 16 + la) * 64;
        qf0 = *(const bf16x8*)(qr1 + g * 8);
        qf1 = *(const bf16x8*)(qr1 + 32 + g * 8);
      }
    }

    __syncthreads();  // vmcnt(0)+lgkmcnt(0): next tile resident, reads done
    cur ^= 1;
  }
}

// ---------------------------------------------------------------------------
// Launcher
// ---------------------------------------------------------------------------
extern "C" void kernel_launch(void* const* d_in, const int* in_sizes, int n_in,
                              void* d_out, int out_size, void* d_ws, size_t ws_size,
                              hipStream_t stream) {
  const float* hidden      = (const float*)d_in[0];
  const float* ln1_g       = (const float*)d_in[1];
  const float* ln1_b       = (const float*)d_in[2];
  const float* w_attn      = (const float*)d_in[3];
  const float* b_attn      = (const float*)d_in[4];
  const float* w_attn_proj = (const float*)d_in[5];
  const float* b_attn_proj = (const float*)d_in[6];
  const float* ln2_g       = (const float*)d_in[7];
  const float* ln2_b       = (const float*)d_in[8];
  const float* w_fc        = (const float*)d_in[9];
  const float* b_fc        = (const float*)d_in[10];
  const float* w_mlp_proj  = (const float*)d_in[11];
  const float* b_mlp_proj  = (const float*)d_in[12];
  float* out = (float*)d_out;

  const int Bn = in_sizes[0] / (SEQ * DMODEL);  // batch (=4)
  const int M = Bn * SEQ;                        // 8192 rows

  // Workspace layout (bytes, ~210MB):
  char* W = (char*)d_ws;
  const size_t szMD2 = (size_t)M * DMODEL * 2;        // 16.8MB
  short* xln_b  = (short*)W;                          // LN out
  short* Vb     = (short*)(W + szMD2);                // V [bh][s][64] (attn phase)
  short* a1_b   = Vb;                                 // later: FF acts [M,FF] bf16
  char*  p2     = W + szMD2 + (size_t)M * FFDIM * 2;
  short* Qb     = (short*)p2;
  short* Kb     = Qb + (size_t)M * DMODEL;
  short* Vtb    = Kb + (size_t)M * DMODEL;
  short* attn_b = Vtb + (size_t)M * DMODEL;
  float* h2     = (float*)(p2 + 4 * szMD2);
  short* wat    = (short*)(p2 + 4 * szMD2 + (size_t)M * DMODEL * 4);
  short* wpt    = wat + (size_t)3 * DMODEL * DMODEL;
  short* wft    = wpt + (size_t)DMODEL * DMODEL;
  short* wmt    = wft + (size_t)FFDIM * DMODEL;
  float* bas    = (float*)(wmt + (size_t)DMODEL * FFDIM);  // scaled b_attn

  // 0. fused weight convert+transpose (+ bias prescale block)
  wconv4_kernel<<<3073, 256, 0, stream>>>(w_attn, wat, w_attn_proj, wpt,
                                          w_fc, wft, w_mlp_proj, wmt,
                                          b_attn, bas);
  // 1. LN1 -> bf16
  ln_kernel<<<M, 256, 0, stream>>>(hidden, ln1_g, ln1_b, xln_b);
  // 2. QKV GEMM (1-D grid 24*64=1536), scatter epilogue (Q pre-scaled)
  gemm_bf16<true, false, false, true><<<24 * 64, 256, 0, stream>>>(
      xln_b, wat, bas, nullptr, Qb, Kb, Vb, M, 3 * DMODEL, DMODEL, 24);
  // 2.5 V transpose only
  prepv_kernel<<<dim3(SEQ / 64, NHEAD, Bn), 256, 0, stream>>>(Vb, Vtb);
  // 3. attention -> bf16 [M,1024]  (paired q-tiles, double-buffered)
  mha_kernel<<<dim3(QT / 2, NHEAD, Bn), 256, 0, stream>>>(Qb, Kb, Vtb, attn_b);
  // 4. h2 = hidden + attn @ w_attn_proj + b   (fp32; grid 8*64=512)
  gemm_bf16<false, false, true, false><<<8 * 64, 256, 0, stream>>>(
      attn_b, wpt, b_attn_proj, hidden, h2, nullptr, nullptr, M, DMODEL, DMODEL, 8);
  // 5. LN2 -> bf16
  ln_kernel<<<M, 256, 0, stream>>>(h2, ln2_g, ln2_b, xln_b);
  // 6. a1 = gelu(xln2 @ w_fc + b) -> bf16 [M,4096]  (grid 32*64=2048)
  gemm_bf16<true, true, false, false><<<32 * 64, 256, 0, stream>>>(
      xln_b, wft, b_fc, nullptr, a1_b, nullptr, nullptr, M, FFDIM, DMODEL, 32);
  // 7. out = h2 + a1 @ w_mlp_proj + b  (fp32; grid 8*64=512)
  gemm_bf16<false, false, true, false><<<8 * 64, 256, 0, stream>>>(
      a1_b, wmt, b_mlp_proj, h2, out, nullptr, nullptr, M, DMODEL, FFDIM, 8);
}